// Round 7
// baseline (738.424 us; speedup 1.0000x reference)
//
#include <hip/hip_runtime.h>

typedef short bf16x8 __attribute__((ext_vector_type(8)));
typedef float f32x4 __attribute__((ext_vector_type(4)));
typedef float f32x2 __attribute__((ext_vector_type(2)));
typedef unsigned short u16;
typedef u16 u16x4 __attribute__((ext_vector_type(4)));

#define L_SEQ 1024
#define IDIM_ 2048
#define H_ 16
#define DK_ 128
#define DV_ 128
#define KEYD 2048
#define VALD 2048
#define CONVD 6144
#define CH 16
#define NCH (L_SEQ / CH)

__device__ __forceinline__ u16 f2bf(float f) {
  union { float f; unsigned u; } v; v.f = f;
  unsigned r = v.u + 0x7FFF + ((v.u >> 16) & 1);  // RNE
  return (u16)(r >> 16);
}

// 16-lane allreduce, all-DPP (VALU only): xor1, xor2, row_half_mirror(==xor4
// once quads uniform), row_mirror(==xor8 once octets uniform). Verified R3-R6.
__device__ __forceinline__ float red16(float x) {
  union U { float f; int i; } a, t;
  a.f = x;
  t.i = __builtin_amdgcn_update_dpp(0, a.i, 0xB1, 0xF, 0xF, true); a.f += t.f;
  t.i = __builtin_amdgcn_update_dpp(0, a.i, 0x4E, 0xF, 0xF, true); a.f += t.f;
  t.i = __builtin_amdgcn_update_dpp(0, a.i, 0x141, 0xF, 0xF, true); a.f += t.f;
  t.i = __builtin_amdgcn_update_dpp(0, a.i, 0x140, 0xF, 0xF, true); a.f += t.f;
  return a.f;
}

__device__ __forceinline__ void gl_lds16(const float* g, float* l) {
  __builtin_amdgcn_global_load_lds(
      (const __attribute__((address_space(1))) void*)g,
      (__attribute__((address_space(3))) void*)l, 16, 0, 0);
}
__device__ __forceinline__ void gl_lds4(const float* g, float* l) {
  __builtin_amdgcn_global_load_lds(
      (const __attribute__((address_space(1))) void*)g,
      (__attribute__((address_space(3))) void*)l, 4, 0, 0);
}

// ---------------- cast x (f32 -> bf16), vectorized x4 ----------------
__global__ __launch_bounds__(256) void castx_kernel(const float* __restrict__ x,
                                                    u16* __restrict__ xb) {
  int i = (blockIdx.x * 256 + threadIdx.x) * 4;
  f32x4 v = *(const f32x4*)&x[i];
  u16x4 o = { f2bf(v[0]), f2bf(v[1]), f2bf(v[2]), f2bf(v[3]) };
  *(u16x4*)&xb[i] = o;
}

// ------------- transpose + cast: W[R][C] f32 -> WT[C][R] bf16 -------------
__global__ __launch_bounds__(256) void tcast_kernel(const float* __restrict__ W,
                                                    u16* __restrict__ WT,
                                                    int R, int C) {
  __shared__ float tile[32][33];
  int c0 = blockIdx.x * 32, r0 = blockIdx.y * 32;
  int tx = threadIdx.x & 31, ty = threadIdx.x >> 5;  // 32 x 8
#pragma unroll
  for (int j = 0; j < 4; ++j)
    tile[ty + j * 8][tx] = W[(size_t)(r0 + ty + j * 8) * C + c0 + tx];
  __syncthreads();
#pragma unroll
  for (int j = 0; j < 4; ++j)
    WT[(size_t)(c0 + ty + j * 8) * R + r0 + tx] = f2bf(tile[tx][ty + j * 8]);
}

// ---------------- NT GEMM: A[M,K] bf16, B[N,K] bf16 -> C[M,N] f32 ----------------
__global__ __launch_bounds__(256) void gemm_bt_kernel(const u16* __restrict__ A,
                                                      const u16* __restrict__ B,
                                                      float* __restrict__ C,
                                                      int M, int N, int K) {
  __shared__ short As[128 * 72];
  __shared__ short Bs[128 * 72];
  const int tid = threadIdx.x;
  const int lane = tid & 63, wave = tid >> 6;
  const int wm = wave >> 1, wn = wave & 1;
  const int m0 = blockIdx.y * 128, n0 = blockIdx.x * 128;
  const int l15 = lane & 15, lhi = lane >> 4;

  f32x4 acc[4][4] = {};

  for (int k0 = 0; k0 < K; k0 += 64) {
    __syncthreads();
#pragma unroll
    for (int i = 0; i < 4; ++i) {
      int chunk = tid + i * 256;
      int row = chunk >> 3;
      int kc = (chunk & 7) * 8;
      *(bf16x8*)&As[row * 72 + kc] =
          *(const bf16x8*)&A[(size_t)(m0 + row) * K + k0 + kc];
      *(bf16x8*)&Bs[row * 72 + kc] =
          *(const bf16x8*)&B[(size_t)(n0 + row) * K + k0 + kc];
    }
    __syncthreads();
#pragma unroll
    for (int kk = 0; kk < 64; kk += 32) {
      const int koff = kk + lhi * 8;
      bf16x8 a[4], b[4];
#pragma unroll
      for (int m = 0; m < 4; ++m)
        a[m] = *(const bf16x8*)&As[(wm * 64 + m * 16 + l15) * 72 + koff];
#pragma unroll
      for (int n = 0; n < 4; ++n)
        b[n] = *(const bf16x8*)&Bs[(wn * 64 + n * 16 + l15) * 72 + koff];
#pragma unroll
      for (int m = 0; m < 4; ++m)
#pragma unroll
        for (int n = 0; n < 4; ++n)
          acc[m][n] = __builtin_amdgcn_mfma_f32_16x16x32_bf16(a[m], b[n], acc[m][n], 0, 0, 0);
    }
  }
#pragma unroll
  for (int m = 0; m < 4; ++m)
#pragma unroll
    for (int n = 0; n < 4; ++n)
#pragma unroll
      for (int j = 0; j < 4; ++j) {
        int row = m0 + wm * 64 + m * 16 + lhi * 4 + j;
        int col = n0 + wn * 64 + n * 16 + l15;
        C[(size_t)row * N + col] = acc[m][n][j];
      }
}

// ---------------- causal depthwise conv (K=4) + SiLU ----------------
__global__ __launch_bounds__(256) void conv_silu_kernel(const float* __restrict__ qkv,
                                                        const float* __restrict__ cw,
                                                        float* __restrict__ qkvc) {
  int idx = blockIdx.x * 256 + threadIdx.x;
  int l = idx / CONVD, c = idx - l * CONVD;
  f32x4 w = *(const f32x4*)&cw[c * 4];
  float s = qkv[idx] * w[3];
  if (l >= 1) s += qkv[idx - CONVD] * w[2];
  if (l >= 2) s += qkv[idx - 2 * CONVD] * w[1];
  if (l >= 3) s += qkv[idx - 3 * CONVD] * w[0];
  qkvc[idx] = s / (1.f + expf(-s));
}

// -------- beta/eg gates, written TRANSPOSED: egT/btT[h*1024 + l] --------
__global__ __launch_bounds__(128) void betag_kernel(const float* __restrict__ x,
                                                    const float* __restrict__ Wb,
                                                    const float* __restrict__ Wa,
                                                    const float* __restrict__ A_log,
                                                    const float* __restrict__ dt_bias,
                                                    float* __restrict__ btT,
                                                    float* __restrict__ egT) {
  int l = blockIdx.x;
  __shared__ float xs[IDIM_];
  __shared__ float redb[128], reda[128];
  for (int i = threadIdx.x; i < IDIM_; i += 128) xs[i] = x[(size_t)l * IDIM_ + i];
  __syncthreads();
  int h = threadIdx.x & 15, part = threadIdx.x >> 4;
  float sb = 0.f, sa = 0.f;
  int d0 = part * 256;
  for (int d = d0; d < d0 + 256; ++d) {
    float xv = xs[d];
    sb += xv * Wb[d * 16 + h];
    sa += xv * Wa[d * 16 + h];
  }
  redb[threadIdx.x] = sb;
  reda[threadIdx.x] = sa;
  __syncthreads();
  if (threadIdx.x < 16) {
    float b = 0.f, a = 0.f;
#pragma unroll
    for (int p = 0; p < 8; ++p) { b += redb[p * 16 + h]; a += reda[p * 16 + h]; }
    btT[h * L_SEQ + l] = 1.f / (1.f + expf(-b));
    float dtv = a + dt_bias[h];
    dtv = (dtv > 20.f) ? dtv : log1pf(expf(dtv));
    float g = -expf(A_log[h]) * dtv;
    egT[h * L_SEQ + l] = expf(g);
  }
}

// ---- l2norm q (scaled) + k, repack to [h][l][dk]; also qkT[h][l] = q.k ----
__global__ __launch_bounds__(256) void l2qk_kernel(const float* __restrict__ qkvc,
                                                   float* __restrict__ qn,
                                                   float* __restrict__ kn,
                                                   float* __restrict__ qkT) {
  int wid = blockIdx.x * 4 + (threadIdx.x >> 6);  // 16384 waves: l*16+h
  int lane = threadIdx.x & 63;
  int l = wid >> 4, h = wid & 15;
  const float* qb = qkvc + (size_t)l * CONVD + h * 128;
  const float* kb = qb + KEYD;
  f32x2 qv = *(const f32x2*)&qb[lane * 2];
  f32x2 kv = *(const f32x2*)&kb[lane * 2];
  float ssq = qv[0] * qv[0] + qv[1] * qv[1];
  float ssk = kv[0] * kv[0] + kv[1] * kv[1];
#pragma unroll
  for (int s = 1; s < 64; s <<= 1) {
    ssq += __shfl_xor(ssq, s);
    ssk += __shfl_xor(ssk, s);
  }
  float scq = 0.08838834764831845f / sqrtf(ssq + 1e-6f);  // * DK^-0.5
  float sck = 1.f / sqrtf(ssk + 1e-6f);
  qv[0] *= scq; qv[1] *= scq;
  kv[0] *= sck; kv[1] *= sck;
  size_t base = ((size_t)h * L_SEQ + l) * 128 + lane * 2;
  *(f32x2*)&qn[base] = qv;
  *(f32x2*)&kn[base] = kv;
  float qk = qv[0] * kv[0] + qv[1] * kv[1];
#pragma unroll
  for (int s = 1; s < 64; s <<= 1) qk += __shfl_xor(qk, s);
  if (lane == 0) qkT[h * L_SEQ + l] = qk;
}

// ---- transpose v slice of qkvc -> vT[c][l], c = h*128+dv ----
__global__ __launch_bounds__(256) void vtrans_kernel(const float* __restrict__ qkvc,
                                                     float* __restrict__ vT) {
  __shared__ float tile[32][33];
  int c0 = blockIdx.x * 32, l0 = blockIdx.y * 32;
  int tx = threadIdx.x & 31, ty = threadIdx.x >> 5;
#pragma unroll
  for (int j = 0; j < 4; ++j)
    tile[ty + j * 8][tx] = qkvc[(size_t)(l0 + ty + j * 8) * CONVD + 2 * KEYD + c0 + tx];
  __syncthreads();
#pragma unroll
  for (int j = 0; j < 4; ++j)
    vT[(size_t)(c0 + ty + j * 8) * L_SEQ + l0 + tx] = tile[tx][ty + j * 8];
}

// ---------------- sequential delta-rule scan v6 ----------------
// P=16 lanes/col. 1024-thr blocks: 16 waves = 64 cols (one head, 64 dv).
// grid = 32 blocks -> 32 CUs x 16 waves = 4 waves/SIMD co-resident:
// 4 independent chains per SIMD hide each other's latency (issue-bound).
// Inner loop bitwise-identical to the R6-passing kernel.
__global__ __launch_bounds__(1024, 4) void scan_kernel(const float* __restrict__ qn,
                                                       const float* __restrict__ kn,
                                                       const float* __restrict__ vT,
                                                       const float* __restrict__ egT,
                                                       const float* __restrict__ btT,
                                                       const float* __restrict__ qkT,
                                                       float* __restrict__ oatt) {
  __shared__ alignas(16) float qs[2][CH][128];
  __shared__ alignas(16) float ks[2][CH][128];
  __shared__ alignas(16) float vs[2][64][CH];
  __shared__ alignas(16) float ebc[2][3][CH];

  const int tid = threadIdx.x;
  const int wave = tid >> 6, lane = tid & 63;
  const int dk_sub = lane & 15;
  const int head = blockIdx.x & 15;       // bid, bid+16 share head AND XCD (16%8==0)
  const int dv0 = (blockIdx.x >> 4) * 64;
  const int col_local = tid >> 4;         // 0..63
  const int dv = dv0 + col_local;

  const float* qh = qn + (size_t)head * L_SEQ * 128;
  const float* kh = kn + (size_t)head * L_SEQ * 128;

  auto stage = [&](int chunk, int buf) {
    const int l0 = chunk * CH;
    // q: waves 0-7 stage seg w; k: waves 8-15 stage seg w-8 (256 floats each)
    if (wave < 8) {
      int off = wave * 256 + lane * 4;
      gl_lds16(qh + (size_t)l0 * 128 + off, &qs[buf][0][0] + wave * 256);
    } else {
      int off = (wave - 8) * 256 + lane * 4;
      gl_lds16(kh + (size_t)l0 * 128 + off, &ks[buf][0][0] + wave * 256 - 2048);
    }
    // v: waves 0-3 stage 16 cols each; lane i: col=16w+(i>>2), 4 floats at (i&3)*4
    if (wave < 4) {
      int col = wave * 16 + (lane >> 2);
      gl_lds16(vT + (size_t)(head * 128 + dv0 + col) * L_SEQ + l0 + (lane & 3) * 4,
               &vs[buf][0][0] + wave * 256);
    }
    if (wave == 4 && lane < 48) {         // e (0-15), beta (16-31), qk (32-47)
      const float* src = (lane < 16) ? (egT + head * L_SEQ + l0 + lane)
                       : (lane < 32) ? (btT + head * L_SEQ + l0 + (lane - 16))
                                     : (qkT + head * L_SEQ + l0 + (lane - 32));
      gl_lds4(src, &ebc[buf][0][0]);      // lane l -> flat [l]
    }
  };

  stage(0, 0);
  __syncthreads();

  f32x4 Mlo = {0.f, 0.f, 0.f, 0.f}, Mhi = {0.f, 0.f, 0.f, 0.f};
  const int dkb = dk_sub * 8;

#pragma unroll 1
  for (int c = 0; c < NCH; ++c) {
    const int buf = c & 1;
    if (c + 1 < NCH) stage(c + 1, buf ^ 1);

    // chunk-start bulk loads: all per-step scalars for 16 steps into regs
    f32x4 ev[4], bv[4], cv[4], vv[4];
#pragma unroll
    for (int i = 0; i < 4; ++i) {
      ev[i] = *(const f32x4*)&ebc[buf][0][i * 4];
      bv[i] = *(const f32x4*)&ebc[buf][1][i * 4];
      cv[i] = *(const f32x4*)&ebc[buf][2][i * 4];
      vv[i] = *(const f32x4*)&vs[buf][col_local][i * 4];
    }
    // q/k ring prefetch, distance 3
    f32x4 qr[4][2], kr[4][2];
#pragma unroll
    for (int i = 0; i < 3; ++i) {
      qr[i][0] = *(const f32x4*)&qs[buf][i][dkb];
      qr[i][1] = *(const f32x4*)&qs[buf][i][dkb + 4];
      kr[i][0] = *(const f32x4*)&ks[buf][i][dkb];
      kr[i][1] = *(const f32x4*)&ks[buf][i][dkb + 4];
    }

#pragma unroll
    for (int s = 0; s < CH; ++s) {
      if (s + 3 < CH) {
        qr[(s + 3) & 3][0] = *(const f32x4*)&qs[buf][s + 3][dkb];
        qr[(s + 3) & 3][1] = *(const f32x4*)&qs[buf][s + 3][dkb + 4];
        kr[(s + 3) & 3][0] = *(const f32x4*)&ks[buf][s + 3][dkb];
        kr[(s + 3) & 3][1] = *(const f32x4*)&ks[buf][s + 3][dkb + 4];
      }
      const f32x4 q0 = qr[s & 3][0], q1 = qr[s & 3][1];
      const f32x4 k0 = kr[s & 3][0], k1 = kr[s & 3][1];
      const float e = ev[s >> 2][s & 3], b = bv[s >> 2][s & 3];
      const float qk = cv[s >> 2][s & 3], v = vv[s >> 2][s & 3];

      // dots on M_old: two independent fma chains each, depth 4+1
      float skm0 = k0[0] * Mlo[0], skm1 = k0[1] * Mlo[1];
      float sqm0 = q0[0] * Mlo[0], sqm1 = q0[1] * Mlo[1];
      skm0 = fmaf(k0[2], Mlo[2], skm0); skm1 = fmaf(k0[3], Mlo[3], skm1);
      sqm0 = fmaf(q0[2], Mlo[2], sqm0); sqm1 = fmaf(q0[3], Mlo[3], sqm1);
      skm0 = fmaf(k1[0], Mhi[0], skm0); skm1 = fmaf(k1[1], Mhi[1], skm1);
      sqm0 = fmaf(q1[0], Mhi[0], sqm0); sqm1 = fmaf(q1[1], Mhi[1], sqm1);
      skm0 = fmaf(k1[2], Mhi[2], skm0); skm1 = fmaf(k1[3], Mhi[3], skm1);
      sqm0 = fmaf(q1[2], Mhi[2], sqm0); sqm1 = fmaf(q1[3], Mhi[3], sqm1);
      // e*M_old off the skm critical path (overlaps red16)
      f32x4 emlo, emhi;
#pragma unroll
      for (int i = 0; i < 4; ++i) { emlo[i] = e * Mlo[i]; emhi[i] = e * Mhi[i]; }
      float skm = red16(skm0 + skm1);
      float sqm = red16(sqm0 + sqm1);
      float dl = (v - e * skm) * b;       // delta
      float o = fmaf(qk, dl, e * sqm);    // q . M_new
      if (dk_sub == 0)
        oatt[(size_t)((c * CH + s) * 16 + head) * 128 + dv] = o;
#pragma unroll
      for (int i = 0; i < 4; ++i) {
        Mlo[i] = fmaf(k0[i], dl, emlo[i]);
        Mhi[i] = fmaf(k1[i], dl, emhi[i]);
      }
    }
    __syncthreads();
  }
}

// ---------------- gated RMSNorm -> bf16 ----------------
__global__ __launch_bounds__(256) void grms_kernel(const float* __restrict__ oatt,
                                                   const float* __restrict__ z,
                                                   const float* __restrict__ norm_w,
                                                   u16* __restrict__ gn) {
  int wid = blockIdx.x * 4 + (threadIdx.x >> 6);
  int lane = threadIdx.x & 63;
  int l = wid >> 4, h = wid & 15;
  const float* o = oatt + (size_t)wid * 128;
  f32x2 ov = *(const f32x2*)&o[lane * 2];
  float ss = ov[0] * ov[0] + ov[1] * ov[1];
#pragma unroll
  for (int s = 1; s < 64; s <<= 1) ss += __shfl_xor(ss, s);
  float r = 1.f / sqrtf(ss * (1.f / 128.f) + 1e-6f);
  const float* zp = z + (size_t)l * VALD + h * 128;
  f32x2 zv = *(const f32x2*)&zp[lane * 2];
  u16 r0, r1;
  {
    float sil = zv[0] / (1.f + expf(-zv[0]));
    r0 = f2bf(ov[0] * r * norm_w[lane * 2] * sil);
    float sil1 = zv[1] / (1.f + expf(-zv[1]));
    r1 = f2bf(ov[1] * r * norm_w[lane * 2 + 1] * sil1);
  }
  u16* dst = gn + (size_t)l * VALD + h * 128 + lane * 2;
  dst[0] = r0; dst[1] = r1;
}

extern "C" void kernel_launch(void* const* d_in, const int* in_sizes, int n_in,
                              void* d_out, int out_size, void* d_ws, size_t ws_size,
                              hipStream_t stream) {
  const float* x      = (const float*)d_in[0];
  const float* Wqkv   = (const float*)d_in[1];
  const float* Wz     = (const float*)d_in[2];
  const float* Wb     = (const float*)d_in[3];
  const float* Wa     = (const float*)d_in[4];
  const float* conv_w = (const float*)d_in[5];
  const float* A_log  = (const float*)d_in[6];
  const float* dt_bias= (const float*)d_in[7];
  const float* norm_w = (const float*)d_in[8];
  const float* Wout   = (const float*)d_in[9];
  float* out = (float*)d_out;

  char* ws = (char*)d_ws;
  size_t off = 0;
  auto alloc = [&](size_t bytes) {
    void* p = ws + off;
    off = (off + bytes + 255) & ~(size_t)255;
    return p;
  };
  u16* xb     = (u16*)alloc((size_t)L_SEQ * IDIM_ * 2);
  u16* WqkvT  = (u16*)alloc((size_t)CONVD * IDIM_ * 2);
  u16* WzT    = (u16*)alloc((size_t)VALD * IDIM_ * 2);
  u16* WoutT  = (u16*)alloc((size_t)IDIM_ * VALD * 2);
  float* qkv  = (float*)alloc((size_t)L_SEQ * CONVD * 4);
  float* qkvc = (float*)alloc((size_t)L_SEQ * CONVD * 4);
  float* zbuf = (float*)alloc((size_t)L_SEQ * VALD * 4);
  float* btT  = (float*)alloc((size_t)L_SEQ * H_ * 4);
  float* egT  = (float*)alloc((size_t)L_SEQ * H_ * 4);
  float* qkTb = (float*)alloc((size_t)L_SEQ * H_ * 4);
  float* oatt = (float*)alloc((size_t)L_SEQ * H_ * DV_ * 4);
  u16* gn     = (u16*)alloc((size_t)L_SEQ * VALD * 2);

  // qn/kn/vT reuse the dead qkv buffer after conv (exact 24MB fit)
  float* qn = qkv;
  float* kn = qn + (size_t)H_ * L_SEQ * 128;
  float* vT = kn + (size_t)H_ * L_SEQ * 128;

  // casts / transposes
  castx_kernel<<<(L_SEQ * IDIM_) / 1024, 256, 0, stream>>>(x, xb);
  tcast_kernel<<<dim3(CONVD / 32, IDIM_ / 32), 256, 0, stream>>>(Wqkv, WqkvT, IDIM_, CONVD);
  tcast_kernel<<<dim3(VALD / 32, IDIM_ / 32), 256, 0, stream>>>(Wz, WzT, IDIM_, VALD);
  tcast_kernel<<<dim3(IDIM_ / 32, VALD / 32), 256, 0, stream>>>(Wout, WoutT, VALD, IDIM_);

  // projections
  gemm_bt_kernel<<<dim3(CONVD / 128, L_SEQ / 128), 256, 0, stream>>>(xb, WqkvT, qkv, L_SEQ, CONVD, IDIM_);
  gemm_bt_kernel<<<dim3(VALD / 128, L_SEQ / 128), 256, 0, stream>>>(xb, WzT, zbuf, L_SEQ, VALD, IDIM_);

  // conv + silu, gates
  conv_silu_kernel<<<(L_SEQ * CONVD) / 256, 256, 0, stream>>>(qkv, conv_w, qkvc);
  betag_kernel<<<L_SEQ, 128, 0, stream>>>(x, Wb, Wa, A_log, dt_bias, btT, egT);

  // repack: q/k l2norm + qk scalar -> [h][l][dk] / qkT[h][l]; v -> [h*128+dv][l]
  l2qk_kernel<<<(L_SEQ * H_) / 4, 256, 0, stream>>>(qkvc, qn, kn, qkTb);
  vtrans_kernel<<<dim3(VALD / 32, L_SEQ / 32), 256, 0, stream>>>(qkvc, vT);

  // sequential scan (32 blocks x 1024 thr: 16 waves/block, 4 waves/SIMD)
  scan_kernel<<<H_ * (DV_ / 64), 1024, 0, stream>>>(qn, kn, vT, egT, btT, qkTb, oatt);

  // gated rmsnorm + final projection
  grms_kernel<<<(L_SEQ * H_) / 4, 256, 0, stream>>>(oatt, zbuf, norm_w, gn);
  gemm_bt_kernel<<<dim3(IDIM_ / 128, L_SEQ / 128), 256, 0, stream>>>(gn, WoutT, out, L_SEQ, IDIM_, VALD);
}

// Round 8
// 453.579 us; speedup vs baseline: 1.6280x; 1.6280x over previous
//
#include <hip/hip_runtime.h>

typedef short bf16x8 __attribute__((ext_vector_type(8)));
typedef float f32x4 __attribute__((ext_vector_type(4)));
typedef float f32x2 __attribute__((ext_vector_type(2)));
typedef unsigned short u16;
typedef u16 u16x4 __attribute__((ext_vector_type(4)));

#define L_SEQ 1024
#define IDIM_ 2048
#define H_ 16
#define DK_ 128
#define DV_ 128
#define KEYD 2048
#define VALD 2048
#define CONVD 6144
#define CH 16
#define NCH (L_SEQ / CH)

__device__ __forceinline__ u16 f2bf(float f) {
  union { float f; unsigned u; } v; v.f = f;
  unsigned r = v.u + 0x7FFF + ((v.u >> 16) & 1);  // RNE
  return (u16)(r >> 16);
}

// 16-lane allreduce, all-DPP (VALU only): xor1, xor2, row_half_mirror(==xor4
// once quads uniform), row_mirror(==xor8 once octets uniform). Verified R3-R7.
__device__ __forceinline__ float red16(float x) {
  union U { float f; int i; } a, t;
  a.f = x;
  t.i = __builtin_amdgcn_update_dpp(0, a.i, 0xB1, 0xF, 0xF, true); a.f += t.f;
  t.i = __builtin_amdgcn_update_dpp(0, a.i, 0x4E, 0xF, 0xF, true); a.f += t.f;
  t.i = __builtin_amdgcn_update_dpp(0, a.i, 0x141, 0xF, 0xF, true); a.f += t.f;
  t.i = __builtin_amdgcn_update_dpp(0, a.i, 0x140, 0xF, 0xF, true); a.f += t.f;
  return a.f;
}

__device__ __forceinline__ void gl_lds16(const float* g, float* l) {
  __builtin_amdgcn_global_load_lds(
      (const __attribute__((address_space(1))) void*)g,
      (__attribute__((address_space(3))) void*)l, 16, 0, 0);
}
__device__ __forceinline__ void gl_lds4(const float* g, float* l) {
  __builtin_amdgcn_global_load_lds(
      (const __attribute__((address_space(1))) void*)g,
      (__attribute__((address_space(3))) void*)l, 4, 0, 0);
}

// ---------------- cast x (f32 -> bf16), vectorized x4 ----------------
__global__ __launch_bounds__(256) void castx_kernel(const float* __restrict__ x,
                                                    u16* __restrict__ xb) {
  int i = (blockIdx.x * 256 + threadIdx.x) * 4;
  f32x4 v = *(const f32x4*)&x[i];
  u16x4 o = { f2bf(v[0]), f2bf(v[1]), f2bf(v[2]), f2bf(v[3]) };
  *(u16x4*)&xb[i] = o;
}

// ------------- transpose + cast: W[R][C] f32 -> WT[C][R] bf16 -------------
__global__ __launch_bounds__(256) void tcast_kernel(const float* __restrict__ W,
                                                    u16* __restrict__ WT,
                                                    int R, int C) {
  __shared__ float tile[32][33];
  int c0 = blockIdx.x * 32, r0 = blockIdx.y * 32;
  int tx = threadIdx.x & 31, ty = threadIdx.x >> 5;  // 32 x 8
#pragma unroll
  for (int j = 0; j < 4; ++j)
    tile[ty + j * 8][tx] = W[(size_t)(r0 + ty + j * 8) * C + c0 + tx];
  __syncthreads();
#pragma unroll
  for (int j = 0; j < 4; ++j)
    WT[(size_t)(c0 + ty + j * 8) * R + r0 + tx] = f2bf(tile[tx][ty + j * 8]);
}

// ---------------- NT GEMM: A[M,K] bf16, B[N,K] bf16 -> C[M,N] f32 ----------------
__global__ __launch_bounds__(256) void gemm_bt_kernel(const u16* __restrict__ A,
                                                      const u16* __restrict__ B,
                                                      float* __restrict__ C,
                                                      int M, int N, int K) {
  __shared__ short As[128 * 72];
  __shared__ short Bs[128 * 72];
  const int tid = threadIdx.x;
  const int lane = tid & 63, wave = tid >> 6;
  const int wm = wave >> 1, wn = wave & 1;
  const int m0 = blockIdx.y * 128, n0 = blockIdx.x * 128;
  const int l15 = lane & 15, lhi = lane >> 4;

  f32x4 acc[4][4] = {};

  for (int k0 = 0; k0 < K; k0 += 64) {
    __syncthreads();
#pragma unroll
    for (int i = 0; i < 4; ++i) {
      int chunk = tid + i * 256;
      int row = chunk >> 3;
      int kc = (chunk & 7) * 8;
      *(bf16x8*)&As[row * 72 + kc] =
          *(const bf16x8*)&A[(size_t)(m0 + row) * K + k0 + kc];
      *(bf16x8*)&Bs[row * 72 + kc] =
          *(const bf16x8*)&B[(size_t)(n0 + row) * K + k0 + kc];
    }
    __syncthreads();
#pragma unroll
    for (int kk = 0; kk < 64; kk += 32) {
      const int koff = kk + lhi * 8;
      bf16x8 a[4], b[4];
#pragma unroll
      for (int m = 0; m < 4; ++m)
        a[m] = *(const bf16x8*)&As[(wm * 64 + m * 16 + l15) * 72 + koff];
#pragma unroll
      for (int n = 0; n < 4; ++n)
        b[n] = *(const bf16x8*)&Bs[(wn * 64 + n * 16 + l15) * 72 + koff];
#pragma unroll
      for (int m = 0; m < 4; ++m)
#pragma unroll
        for (int n = 0; n < 4; ++n)
          acc[m][n] = __builtin_amdgcn_mfma_f32_16x16x32_bf16(a[m], b[n], acc[m][n], 0, 0, 0);
    }
  }
#pragma unroll
  for (int m = 0; m < 4; ++m)
#pragma unroll
    for (int n = 0; n < 4; ++n)
#pragma unroll
      for (int j = 0; j < 4; ++j) {
        int row = m0 + wm * 64 + m * 16 + lhi * 4 + j;
        int col = n0 + wn * 64 + n * 16 + l15;
        C[(size_t)row * N + col] = acc[m][n][j];
      }
}

// ---------------- causal depthwise conv (K=4) + SiLU ----------------
__global__ __launch_bounds__(256) void conv_silu_kernel(const float* __restrict__ qkv,
                                                        const float* __restrict__ cw,
                                                        float* __restrict__ qkvc) {
  int idx = blockIdx.x * 256 + threadIdx.x;
  int l = idx / CONVD, c = idx - l * CONVD;
  f32x4 w = *(const f32x4*)&cw[c * 4];
  float s = qkv[idx] * w[3];
  if (l >= 1) s += qkv[idx - CONVD] * w[2];
  if (l >= 2) s += qkv[idx - 2 * CONVD] * w[1];
  if (l >= 3) s += qkv[idx - 3 * CONVD] * w[0];
  qkvc[idx] = s / (1.f + expf(-s));
}

// -------- beta/eg gates, written TRANSPOSED: egT/btT[h*1024 + l] --------
__global__ __launch_bounds__(128) void betag_kernel(const float* __restrict__ x,
                                                    const float* __restrict__ Wb,
                                                    const float* __restrict__ Wa,
                                                    const float* __restrict__ A_log,
                                                    const float* __restrict__ dt_bias,
                                                    float* __restrict__ btT,
                                                    float* __restrict__ egT) {
  int l = blockIdx.x;
  __shared__ float xs[IDIM_];
  __shared__ float redb[128], reda[128];
  for (int i = threadIdx.x; i < IDIM_; i += 128) xs[i] = x[(size_t)l * IDIM_ + i];
  __syncthreads();
  int h = threadIdx.x & 15, part = threadIdx.x >> 4;
  float sb = 0.f, sa = 0.f;
  int d0 = part * 256;
  for (int d = d0; d < d0 + 256; ++d) {
    float xv = xs[d];
    sb += xv * Wb[d * 16 + h];
    sa += xv * Wa[d * 16 + h];
  }
  redb[threadIdx.x] = sb;
  reda[threadIdx.x] = sa;
  __syncthreads();
  if (threadIdx.x < 16) {
    float b = 0.f, a = 0.f;
#pragma unroll
    for (int p = 0; p < 8; ++p) { b += redb[p * 16 + h]; a += reda[p * 16 + h]; }
    btT[h * L_SEQ + l] = 1.f / (1.f + expf(-b));
    float dtv = a + dt_bias[h];
    dtv = (dtv > 20.f) ? dtv : log1pf(expf(dtv));
    float g = -expf(A_log[h]) * dtv;
    egT[h * L_SEQ + l] = expf(g);
  }
}

// ---- l2norm q (scaled) + k, repack to [h][l][dk]; also qkT[h][l] = q.k ----
__global__ __launch_bounds__(256) void l2qk_kernel(const float* __restrict__ qkvc,
                                                   float* __restrict__ qn,
                                                   float* __restrict__ kn,
                                                   float* __restrict__ qkT) {
  int wid = blockIdx.x * 4 + (threadIdx.x >> 6);  // 16384 waves: l*16+h
  int lane = threadIdx.x & 63;
  int l = wid >> 4, h = wid & 15;
  const float* qb = qkvc + (size_t)l * CONVD + h * 128;
  const float* kb = qb + KEYD;
  f32x2 qv = *(const f32x2*)&qb[lane * 2];
  f32x2 kv = *(const f32x2*)&kb[lane * 2];
  float ssq = qv[0] * qv[0] + qv[1] * qv[1];
  float ssk = kv[0] * kv[0] + kv[1] * kv[1];
#pragma unroll
  for (int s = 1; s < 64; s <<= 1) {
    ssq += __shfl_xor(ssq, s);
    ssk += __shfl_xor(ssk, s);
  }
  float scq = 0.08838834764831845f / sqrtf(ssq + 1e-6f);  // * DK^-0.5
  float sck = 1.f / sqrtf(ssk + 1e-6f);
  qv[0] *= scq; qv[1] *= scq;
  kv[0] *= sck; kv[1] *= sck;
  size_t base = ((size_t)h * L_SEQ + l) * 128 + lane * 2;
  *(f32x2*)&qn[base] = qv;
  *(f32x2*)&kn[base] = kv;
  float qk = qv[0] * kv[0] + qv[1] * kv[1];
#pragma unroll
  for (int s = 1; s < 64; s <<= 1) qk += __shfl_xor(qk, s);
  if (lane == 0) qkT[h * L_SEQ + l] = qk;
}

// ---- transpose v slice of qkvc -> vT[c][l], c = h*128+dv ----
__global__ __launch_bounds__(256) void vtrans_kernel(const float* __restrict__ qkvc,
                                                     float* __restrict__ vT) {
  __shared__ float tile[32][33];
  int c0 = blockIdx.x * 32, l0 = blockIdx.y * 32;
  int tx = threadIdx.x & 31, ty = threadIdx.x >> 5;
#pragma unroll
  for (int j = 0; j < 4; ++j)
    tile[ty + j * 8][tx] = qkvc[(size_t)(l0 + ty + j * 8) * CONVD + 2 * KEYD + c0 + tx];
  __syncthreads();
#pragma unroll
  for (int j = 0; j < 4; ++j)
    vT[(size_t)(c0 + ty + j * 8) * L_SEQ + l0 + tx] = tile[tx][ty + j * 8];
}

// ---------------- sequential delta-rule scan v7 ----------------
// P=16 lanes/col; each 16-lane group runs TWO independent columns (ILP):
// chains A,B share q/k reads (same head); only v/state/output duplicate.
// 4 waves/block = 16 slots x 2 cols = 32 cols. grid = 64 blocks -> 64 CUs,
// 1 wave/SIMD on 256 SIMDs; LDS pipe load ~200cyc/CU/step (benign).
__global__ __launch_bounds__(256) void scan_kernel(const float* __restrict__ qn,
                                                   const float* __restrict__ kn,
                                                   const float* __restrict__ vT,
                                                   const float* __restrict__ egT,
                                                   const float* __restrict__ btT,
                                                   const float* __restrict__ qkT,
                                                   float* __restrict__ oatt) {
  __shared__ alignas(16) float qs[2][CH][128];
  __shared__ alignas(16) float ks[2][CH][128];
  __shared__ alignas(16) float vs[2][32][CH];
  __shared__ alignas(16) float ebc[2][3][CH];

  const int tid = threadIdx.x;
  const int wave = tid >> 6, lane = tid & 63;
  const int dk_sub = lane & 15;
  const int head = blockIdx.x & 15;       // consecutive blocks -> different heads
  const int dv0 = (blockIdx.x >> 4) * 32;
  const int slot = tid >> 4;              // 0..15; colA = slot, colB = slot+16
  const int dvA = dv0 + slot, dvB = dv0 + slot + 16;

  const float* qh = qn + (size_t)head * L_SEQ * 128;
  const float* kh = kn + (size_t)head * L_SEQ * 128;

  auto stage = [&](int chunk, int buf) {
    const int l0 = chunk * CH;
    const float* qg = qh + (size_t)l0 * 128;
    const float* kg = kh + (size_t)l0 * 128;
#pragma unroll
    for (int i = 0; i < 2; ++i) {
      int seg = i * 4 + wave;             // 8 segments of 256 floats
      int off = seg * 256 + lane * 4;
      gl_lds16(qg + off, &qs[buf][0][0] + seg * 256);
      gl_lds16(kg + off, &ks[buf][0][0] + seg * 256);
    }
    if (wave < 2) {   // v: 32 cols x CH = 512 floats; wave w stages 16 cols
      int col = wave * 16 + (lane >> 2);  // 4 lanes per col, 4 floats each
      gl_lds16(vT + (size_t)(head * 128 + dv0 + col) * L_SEQ + l0 + (lane & 3) * 4,
               &vs[buf][0][0] + wave * 256);
    }
    if (wave == 2 && lane < 48) {         // e (0-15), beta (16-31), qk (32-47)
      const float* src = (lane < 16) ? (egT + head * L_SEQ + l0 + lane)
                       : (lane < 32) ? (btT + head * L_SEQ + l0 + (lane - 16))
                                     : (qkT + head * L_SEQ + l0 + (lane - 32));
      gl_lds4(src, &ebc[buf][0][0]);      // lane l -> flat [l]
    }
  };

  stage(0, 0);
  __syncthreads();

  f32x4 MloA = {0.f, 0.f, 0.f, 0.f}, MhiA = {0.f, 0.f, 0.f, 0.f};
  f32x4 MloB = {0.f, 0.f, 0.f, 0.f}, MhiB = {0.f, 0.f, 0.f, 0.f};
  const int dkb = dk_sub * 8;

#pragma unroll 1
  for (int c = 0; c < NCH; ++c) {
    const int buf = c & 1;
    if (c + 1 < NCH) stage(c + 1, buf ^ 1);

    // chunk-start bulk loads: all per-step scalars for 16 steps into regs
    f32x4 ev[4], bv[4], cv[4], vvA[4], vvB[4];
#pragma unroll
    for (int i = 0; i < 4; ++i) {
      ev[i] = *(const f32x4*)&ebc[buf][0][i * 4];
      bv[i] = *(const f32x4*)&ebc[buf][1][i * 4];
      cv[i] = *(const f32x4*)&ebc[buf][2][i * 4];
      vvA[i] = *(const f32x4*)&vs[buf][slot][i * 4];
      vvB[i] = *(const f32x4*)&vs[buf][slot + 16][i * 4];
    }
    // q/k ring prefetch, distance 3 (shared by both chains)
    f32x4 qr[4][2], kr[4][2];
#pragma unroll
    for (int i = 0; i < 3; ++i) {
      qr[i][0] = *(const f32x4*)&qs[buf][i][dkb];
      qr[i][1] = *(const f32x4*)&qs[buf][i][dkb + 4];
      kr[i][0] = *(const f32x4*)&ks[buf][i][dkb];
      kr[i][1] = *(const f32x4*)&ks[buf][i][dkb + 4];
    }

#pragma unroll
    for (int s = 0; s < CH; ++s) {
      if (s + 3 < CH) {
        qr[(s + 3) & 3][0] = *(const f32x4*)&qs[buf][s + 3][dkb];
        qr[(s + 3) & 3][1] = *(const f32x4*)&qs[buf][s + 3][dkb + 4];
        kr[(s + 3) & 3][0] = *(const f32x4*)&ks[buf][s + 3][dkb];
        kr[(s + 3) & 3][1] = *(const f32x4*)&ks[buf][s + 3][dkb + 4];
      }
      const f32x4 q0 = qr[s & 3][0], q1 = qr[s & 3][1];
      const f32x4 k0 = kr[s & 3][0], k1 = kr[s & 3][1];
      const float e = ev[s >> 2][s & 3], b = bv[s >> 2][s & 3];
      const float qk = cv[s >> 2][s & 3];
      const float vA = vvA[s >> 2][s & 3], vB = vvB[s >> 2][s & 3];

      // ---- chain A dots ----
      float skmA0 = k0[0] * MloA[0], skmA1 = k0[1] * MloA[1];
      float sqmA0 = q0[0] * MloA[0], sqmA1 = q0[1] * MloA[1];
      skmA0 = fmaf(k0[2], MloA[2], skmA0); skmA1 = fmaf(k0[3], MloA[3], skmA1);
      sqmA0 = fmaf(q0[2], MloA[2], sqmA0); sqmA1 = fmaf(q0[3], MloA[3], sqmA1);
      skmA0 = fmaf(k1[0], MhiA[0], skmA0); skmA1 = fmaf(k1[1], MhiA[1], skmA1);
      sqmA0 = fmaf(q1[0], MhiA[0], sqmA0); sqmA1 = fmaf(q1[1], MhiA[1], sqmA1);
      skmA0 = fmaf(k1[2], MhiA[2], skmA0); skmA1 = fmaf(k1[3], MhiA[3], skmA1);
      sqmA0 = fmaf(q1[2], MhiA[2], sqmA0); sqmA1 = fmaf(q1[3], MhiA[3], sqmA1);
      // ---- chain B dots (independent -> interleaves with A's latency) ----
      float skmB0 = k0[0] * MloB[0], skmB1 = k0[1] * MloB[1];
      float sqmB0 = q0[0] * MloB[0], sqmB1 = q0[1] * MloB[1];
      skmB0 = fmaf(k0[2], MloB[2], skmB0); skmB1 = fmaf(k0[3], MloB[3], skmB1);
      sqmB0 = fmaf(q0[2], MloB[2], sqmB0); sqmB1 = fmaf(q0[3], MloB[3], sqmB1);
      skmB0 = fmaf(k1[0], MhiB[0], skmB0); skmB1 = fmaf(k1[1], MhiB[1], skmB1);
      sqmB0 = fmaf(q1[0], MhiB[0], sqmB0); sqmB1 = fmaf(q1[1], MhiB[1], sqmB1);
      skmB0 = fmaf(k1[2], MhiB[2], skmB0); skmB1 = fmaf(k1[3], MhiB[3], skmB1);
      sqmB0 = fmaf(q1[2], MhiB[2], sqmB0); sqmB1 = fmaf(q1[3], MhiB[3], sqmB1);
      // e*M_old off the critical path (overlaps red16)
      f32x4 emloA, emhiA, emloB, emhiB;
#pragma unroll
      for (int i = 0; i < 4; ++i) {
        emloA[i] = e * MloA[i]; emhiA[i] = e * MhiA[i];
        emloB[i] = e * MloB[i]; emhiB[i] = e * MhiB[i];
      }
      float skmA = red16(skmA0 + skmA1);
      float skmB = red16(skmB0 + skmB1);
      float sqmA = red16(sqmA0 + sqmA1);
      float sqmB = red16(sqmB0 + sqmB1);
      float dlA = (vA - e * skmA) * b;
      float dlB = (vB - e * skmB) * b;
      float oA = fmaf(qk, dlA, e * sqmA);
      float oB = fmaf(qk, dlB, e * sqmB);
      if (dk_sub == 0) {
        float* orow = oatt + (size_t)((c * CH + s) * 16 + head) * 128;
        orow[dvA] = oA;
        orow[dvB] = oB;
      }
#pragma unroll
      for (int i = 0; i < 4; ++i) {
        MloA[i] = fmaf(k0[i], dlA, emloA[i]);
        MhiA[i] = fmaf(k1[i], dlA, emhiA[i]);
        MloB[i] = fmaf(k0[i], dlB, emloB[i]);
        MhiB[i] = fmaf(k1[i], dlB, emhiB[i]);
      }
    }
    __syncthreads();
  }
}

// ---------------- gated RMSNorm -> bf16 ----------------
__global__ __launch_bounds__(256) void grms_kernel(const float* __restrict__ oatt,
                                                   const float* __restrict__ z,
                                                   const float* __restrict__ norm_w,
                                                   u16* __restrict__ gn) {
  int wid = blockIdx.x * 4 + (threadIdx.x >> 6);
  int lane = threadIdx.x & 63;
  int l = wid >> 4, h = wid & 15;
  const float* o = oatt + (size_t)wid * 128;
  f32x2 ov = *(const f32x2*)&o[lane * 2];
  float ss = ov[0] * ov[0] + ov[1] * ov[1];
#pragma unroll
  for (int s = 1; s < 64; s <<= 1) ss += __shfl_xor(ss, s);
  float r = 1.f / sqrtf(ss * (1.f / 128.f) + 1e-6f);
  const float* zp = z + (size_t)l * VALD + h * 128;
  f32x2 zv = *(const f32x2*)&zp[lane * 2];
  u16 r0, r1;
  {
    float sil = zv[0] / (1.f + expf(-zv[0]));
    r0 = f2bf(ov[0] * r * norm_w[lane * 2] * sil);
    float sil1 = zv[1] / (1.f + expf(-zv[1]));
    r1 = f2bf(ov[1] * r * norm_w[lane * 2 + 1] * sil1);
  }
  u16* dst = gn + (size_t)l * VALD + h * 128 + lane * 2;
  dst[0] = r0; dst[1] = r1;
}

extern "C" void kernel_launch(void* const* d_in, const int* in_sizes, int n_in,
                              void* d_out, int out_size, void* d_ws, size_t ws_size,
                              hipStream_t stream) {
  const float* x      = (const float*)d_in[0];
  const float* Wqkv   = (const float*)d_in[1];
  const float* Wz     = (const float*)d_in[2];
  const float* Wb     = (const float*)d_in[3];
  const float* Wa     = (const float*)d_in[4];
  const float* conv_w = (const float*)d_in[5];
  const float* A_log  = (const float*)d_in[6];
  const float* dt_bias= (const float*)d_in[7];
  const float* norm_w = (const float*)d_in[8];
  const float* Wout   = (const float*)d_in[9];
  float* out = (float*)d_out;

  char* ws = (char*)d_ws;
  size_t off = 0;
  auto alloc = [&](size_t bytes) {
    void* p = ws + off;
    off = (off + bytes + 255) & ~(size_t)255;
    return p;
  };
  u16* xb     = (u16*)alloc((size_t)L_SEQ * IDIM_ * 2);
  u16* WqkvT  = (u16*)alloc((size_t)CONVD * IDIM_ * 2);
  u16* WzT    = (u16*)alloc((size_t)VALD * IDIM_ * 2);
  u16* WoutT  = (u16*)alloc((size_t)IDIM_ * VALD * 2);
  float* qkv  = (float*)alloc((size_t)L_SEQ * CONVD * 4);
  float* qkvc = (float*)alloc((size_t)L_SEQ * CONVD * 4);
  float* zbuf = (float*)alloc((size_t)L_SEQ * VALD * 4);
  float* btT  = (float*)alloc((size_t)L_SEQ * H_ * 4);
  float* egT  = (float*)alloc((size_t)L_SEQ * H_ * 4);
  float* qkTb = (float*)alloc((size_t)L_SEQ * H_ * 4);
  float* oatt = (float*)alloc((size_t)L_SEQ * H_ * DV_ * 4);
  u16* gn     = (u16*)alloc((size_t)L_SEQ * VALD * 2);

  // qn/kn/vT reuse the dead qkv buffer after conv (exact 24MB fit)
  float* qn = qkv;
  float* kn = qn + (size_t)H_ * L_SEQ * 128;
  float* vT = kn + (size_t)H_ * L_SEQ * 128;

  // casts / transposes
  castx_kernel<<<(L_SEQ * IDIM_) / 1024, 256, 0, stream>>>(x, xb);
  tcast_kernel<<<dim3(CONVD / 32, IDIM_ / 32), 256, 0, stream>>>(Wqkv, WqkvT, IDIM_, CONVD);
  tcast_kernel<<<dim3(VALD / 32, IDIM_ / 32), 256, 0, stream>>>(Wz, WzT, IDIM_, VALD);
  tcast_kernel<<<dim3(IDIM_ / 32, VALD / 32), 256, 0, stream>>>(Wout, WoutT, VALD, IDIM_);

  // projections
  gemm_bt_kernel<<<dim3(CONVD / 128, L_SEQ / 128), 256, 0, stream>>>(xb, WqkvT, qkv, L_SEQ, CONVD, IDIM_);
  gemm_bt_kernel<<<dim3(VALD / 128, L_SEQ / 128), 256, 0, stream>>>(xb, WzT, zbuf, L_SEQ, VALD, IDIM_);

  // conv + silu, gates
  conv_silu_kernel<<<(L_SEQ * CONVD) / 256, 256, 0, stream>>>(qkv, conv_w, qkvc);
  betag_kernel<<<L_SEQ, 128, 0, stream>>>(x, Wb, Wa, A_log, dt_bias, btT, egT);

  // repack: q/k l2norm + qk scalar -> [h][l][dk] / qkT[h][l]; v -> [h*128+dv][l]
  l2qk_kernel<<<(L_SEQ * H_) / 4, 256, 0, stream>>>(qkvc, qn, kn, qkTb);
  vtrans_kernel<<<dim3(VALD / 32, L_SEQ / 32), 256, 0, stream>>>(qkvc, vT);

  // sequential scan (64 blocks x 256 thr; 2 columns per 16-lane group)
  scan_kernel<<<H_ * (DV_ / 32), 256, 0, stream>>>(qn, kn, vT, egT, btT, qkTb, oatt);

  // gated rmsnorm + final projection
  grms_kernel<<<(L_SEQ * H_) / 4, 256, 0, stream>>>(oatt, zbuf, norm_w, gn);
  gemm_bt_kernel<<<dim3(IDIM_ / 128, L_SEQ / 128), 256, 0, stream>>>(gn, WoutT, out, L_SEQ, IDIM_, VALD);
}

// Round 9
// 409.169 us; speedup vs baseline: 1.8047x; 1.1085x over previous
//
#include <hip/hip_runtime.h>

typedef short bf16x8 __attribute__((ext_vector_type(8)));
typedef float f32x4 __attribute__((ext_vector_type(4)));
typedef float f32x2 __attribute__((ext_vector_type(2)));
typedef unsigned short u16;
typedef u16 u16x4 __attribute__((ext_vector_type(4)));

#define L_SEQ 1024
#define IDIM_ 2048
#define H_ 16
#define DK_ 128
#define DV_ 128
#define KEYD 2048
#define VALD 2048
#define CONVD 6144
#define CH 16
#define NCH (L_SEQ / CH)

__device__ __forceinline__ u16 f2bf(float f) {
  union { float f; unsigned u; } v; v.f = f;
  unsigned r = v.u + 0x7FFF + ((v.u >> 16) & 1);  // RNE
  return (u16)(r >> 16);
}

// 16-lane allreduce, all-DPP (VALU only): xor1, xor2, row_half_mirror(==xor4
// once quads uniform), row_mirror(==xor8 once octets uniform). Verified R3-R8.
__device__ __forceinline__ float red16(float x) {
  union U { float f; int i; } a, t;
  a.f = x;
  t.i = __builtin_amdgcn_update_dpp(0, a.i, 0xB1, 0xF, 0xF, true); a.f += t.f;
  t.i = __builtin_amdgcn_update_dpp(0, a.i, 0x4E, 0xF, 0xF, true); a.f += t.f;
  t.i = __builtin_amdgcn_update_dpp(0, a.i, 0x141, 0xF, 0xF, true); a.f += t.f;
  t.i = __builtin_amdgcn_update_dpp(0, a.i, 0x140, 0xF, 0xF, true); a.f += t.f;
  return a.f;
}

__device__ __forceinline__ void gl_lds16(const float* g, float* l) {
  __builtin_amdgcn_global_load_lds(
      (const __attribute__((address_space(1))) void*)g,
      (__attribute__((address_space(3))) void*)l, 16, 0, 0);
}
__device__ __forceinline__ void gl_lds4(const float* g, float* l) {
  __builtin_amdgcn_global_load_lds(
      (const __attribute__((address_space(1))) void*)g,
      (__attribute__((address_space(3))) void*)l, 4, 0, 0);
}
__device__ __forceinline__ void gl_lds16u(const u16* g, u16* l) {
  __builtin_amdgcn_global_load_lds(
      (const __attribute__((address_space(1))) void*)g,
      (__attribute__((address_space(3))) void*)l, 16, 0, 0);
}

// ---------------- cast x (f32 -> bf16), vectorized x4 ----------------
__global__ __launch_bounds__(256) void castx_kernel(const float* __restrict__ x,
                                                    u16* __restrict__ xb) {
  int i = (blockIdx.x * 256 + threadIdx.x) * 4;
  f32x4 v = *(const f32x4*)&x[i];
  u16x4 o = { f2bf(v[0]), f2bf(v[1]), f2bf(v[2]), f2bf(v[3]) };
  *(u16x4*)&xb[i] = o;
}

// ------------- transpose + cast: W[R][C] f32 -> WT[C][R] bf16 -------------
__global__ __launch_bounds__(256) void tcast_kernel(const float* __restrict__ W,
                                                    u16* __restrict__ WT,
                                                    int R, int C) {
  __shared__ float tile[32][33];
  int c0 = blockIdx.x * 32, r0 = blockIdx.y * 32;
  int tx = threadIdx.x & 31, ty = threadIdx.x >> 5;  // 32 x 8
#pragma unroll
  for (int j = 0; j < 4; ++j)
    tile[ty + j * 8][tx] = W[(size_t)(r0 + ty + j * 8) * C + c0 + tx];
  __syncthreads();
#pragma unroll
  for (int j = 0; j < 4; ++j)
    WT[(size_t)(c0 + ty + j * 8) * R + r0 + tx] = f2bf(tile[tx][ty + j * 8]);
}

// ---------------- NT GEMM (m97-style): A[M,K] bf16, B[N,K] bf16 -> C[M,N] f32 ----
// 128x128 tile, BK=64, 4 waves (2x2 of 64x64). global_load_lds width=16 staging
// into LINEAR [128][64] LDS (gl_lds requires linear dest). MFMA order identical
// to previous version -> bitwise-identical C.
__global__ __launch_bounds__(256) void gemm_bt_kernel(const u16* __restrict__ A,
                                                      const u16* __restrict__ B,
                                                      float* __restrict__ C,
                                                      int M, int N, int K) {
  __shared__ u16 As[128 * 64];
  __shared__ u16 Bs[128 * 64];
  const int tid = threadIdx.x;
  const int lane = tid & 63, wave = tid >> 6;
  const int wm = wave >> 1, wn = wave & 1;
  const int m0 = blockIdx.y * 128, n0 = blockIdx.x * 128;
  const int l15 = lane & 15, lhi = lane >> 4;

  f32x4 acc[4][4] = {};

  // per-thread staging chunk indices (4 chunks of 16B per matrix per K-step)
  for (int k0 = 0; k0 < K; k0 += 64) {
    __syncthreads();
#pragma unroll
    for (int i = 0; i < 4; ++i) {
      int c = tid + i * 256;              // 0..1023
      int row = c >> 3;                   // 128 rows
      int kc = (c & 7) * 8;               // 8 chunks of 8 bf16 per row
      gl_lds16u(A + (size_t)(m0 + row) * K + k0 + kc, &As[c * 8]);
      gl_lds16u(B + (size_t)(n0 + row) * K + k0 + kc, &Bs[c * 8]);
    }
    __syncthreads();
#pragma unroll
    for (int kk = 0; kk < 64; kk += 32) {
      const int koff = kk + lhi * 8;
      bf16x8 a[4], b[4];
#pragma unroll
      for (int m = 0; m < 4; ++m)
        a[m] = *(const bf16x8*)&As[(wm * 64 + m * 16 + l15) * 64 + koff];
#pragma unroll
      for (int n = 0; n < 4; ++n)
        b[n] = *(const bf16x8*)&Bs[(wn * 64 + n * 16 + l15) * 64 + koff];
#pragma unroll
      for (int m = 0; m < 4; ++m)
#pragma unroll
        for (int n = 0; n < 4; ++n)
          acc[m][n] = __builtin_amdgcn_mfma_f32_16x16x32_bf16(a[m], b[n], acc[m][n], 0, 0, 0);
    }
  }
#pragma unroll
  for (int m = 0; m < 4; ++m)
#pragma unroll
    for (int n = 0; n < 4; ++n)
#pragma unroll
      for (int j = 0; j < 4; ++j) {
        int row = m0 + wm * 64 + m * 16 + lhi * 4 + j;
        int col = n0 + wn * 64 + n * 16 + l15;
        C[(size_t)row * N + col] = acc[m][n][j];
      }
}

// ---------------- causal depthwise conv (K=4) + SiLU ----------------
__global__ __launch_bounds__(256) void conv_silu_kernel(const float* __restrict__ qkv,
                                                        const float* __restrict__ cw,
                                                        float* __restrict__ qkvc) {
  int idx = blockIdx.x * 256 + threadIdx.x;
  int l = idx / CONVD, c = idx - l * CONVD;
  f32x4 w = *(const f32x4*)&cw[c * 4];
  float s = qkv[idx] * w[3];
  if (l >= 1) s += qkv[idx - CONVD] * w[2];
  if (l >= 2) s += qkv[idx - 2 * CONVD] * w[1];
  if (l >= 3) s += qkv[idx - 3 * CONVD] * w[0];
  qkvc[idx] = s / (1.f + expf(-s));
}

// -------- beta/eg gates, written TRANSPOSED: egT/btT[h*1024 + l] --------
__global__ __launch_bounds__(128) void betag_kernel(const float* __restrict__ x,
                                                    const float* __restrict__ Wb,
                                                    const float* __restrict__ Wa,
                                                    const float* __restrict__ A_log,
                                                    const float* __restrict__ dt_bias,
                                                    float* __restrict__ btT,
                                                    float* __restrict__ egT) {
  int l = blockIdx.x;
  __shared__ float xs[IDIM_];
  __shared__ float redb[128], reda[128];
  for (int i = threadIdx.x; i < IDIM_; i += 128) xs[i] = x[(size_t)l * IDIM_ + i];
  __syncthreads();
  int h = threadIdx.x & 15, part = threadIdx.x >> 4;
  float sb = 0.f, sa = 0.f;
  int d0 = part * 256;
  for (int d = d0; d < d0 + 256; ++d) {
    float xv = xs[d];
    sb += xv * Wb[d * 16 + h];
    sa += xv * Wa[d * 16 + h];
  }
  redb[threadIdx.x] = sb;
  reda[threadIdx.x] = sa;
  __syncthreads();
  if (threadIdx.x < 16) {
    float b = 0.f, a = 0.f;
#pragma unroll
    for (int p = 0; p < 8; ++p) { b += redb[p * 16 + h]; a += reda[p * 16 + h]; }
    btT[h * L_SEQ + l] = 1.f / (1.f + expf(-b));
    float dtv = a + dt_bias[h];
    dtv = (dtv > 20.f) ? dtv : log1pf(expf(dtv));
    float g = -expf(A_log[h]) * dtv;
    egT[h * L_SEQ + l] = expf(g);
  }
}

// ---- l2norm q (scaled) + k, repack to [h][l][dk]; also qkT[h][l] = q.k ----
__global__ __launch_bounds__(256) void l2qk_kernel(const float* __restrict__ qkvc,
                                                   float* __restrict__ qn,
                                                   float* __restrict__ kn,
                                                   float* __restrict__ qkT) {
  int wid = blockIdx.x * 4 + (threadIdx.x >> 6);  // 16384 waves: l*16+h
  int lane = threadIdx.x & 63;
  int l = wid >> 4, h = wid & 15;
  const float* qb = qkvc + (size_t)l * CONVD + h * 128;
  const float* kb = qb + KEYD;
  f32x2 qv = *(const f32x2*)&qb[lane * 2];
  f32x2 kv = *(const f32x2*)&kb[lane * 2];
  float ssq = qv[0] * qv[0] + qv[1] * qv[1];
  float ssk = kv[0] * kv[0] + kv[1] * kv[1];
#pragma unroll
  for (int s = 1; s < 64; s <<= 1) {
    ssq += __shfl_xor(ssq, s);
    ssk += __shfl_xor(ssk, s);
  }
  float scq = 0.08838834764831845f / sqrtf(ssq + 1e-6f);  // * DK^-0.5
  float sck = 1.f / sqrtf(ssk + 1e-6f);
  qv[0] *= scq; qv[1] *= scq;
  kv[0] *= sck; kv[1] *= sck;
  size_t base = ((size_t)h * L_SEQ + l) * 128 + lane * 2;
  *(f32x2*)&qn[base] = qv;
  *(f32x2*)&kn[base] = kv;
  float qk = qv[0] * kv[0] + qv[1] * kv[1];
#pragma unroll
  for (int s = 1; s < 64; s <<= 1) qk += __shfl_xor(qk, s);
  if (lane == 0) qkT[h * L_SEQ + l] = qk;
}

// ---- transpose v slice of qkvc -> vT[c][l], c = h*128+dv ----
__global__ __launch_bounds__(256) void vtrans_kernel(const float* __restrict__ qkvc,
                                                     float* __restrict__ vT) {
  __shared__ float tile[32][33];
  int c0 = blockIdx.x * 32, l0 = blockIdx.y * 32;
  int tx = threadIdx.x & 31, ty = threadIdx.x >> 5;
#pragma unroll
  for (int j = 0; j < 4; ++j)
    tile[ty + j * 8][tx] = qkvc[(size_t)(l0 + ty + j * 8) * CONVD + 2 * KEYD + c0 + tx];
  __syncthreads();
#pragma unroll
  for (int j = 0; j < 4; ++j)
    vT[(size_t)(c0 + ty + j * 8) * L_SEQ + l0 + tx] = tile[tx][ty + j * 8];
}

// ---------------- sequential delta-rule scan (R6-exact, 164us known-good) ----
// P=16 lanes/col, 4 cols/wave, 4 waves/block = 16 cols (one head, 16 dv).
// grid = 128 blocks. red16 completes the column reduce. All staging via
// global_load_lds; chunk-start bulk scalar loads; q/k ring prefetch dist 3.
__global__ __launch_bounds__(256) void scan_kernel(const float* __restrict__ qn,
                                                   const float* __restrict__ kn,
                                                   const float* __restrict__ vT,
                                                   const float* __restrict__ egT,
                                                   const float* __restrict__ btT,
                                                   const float* __restrict__ qkT,
                                                   float* __restrict__ oatt) {
  __shared__ alignas(16) float qs[2][CH][128];
  __shared__ alignas(16) float ks[2][CH][128];
  __shared__ alignas(16) float vs[2][16][CH];
  __shared__ alignas(16) float ebc[2][3][CH];

  const int tid = threadIdx.x;
  const int wave = tid >> 6, lane = tid & 63;
  const int dk_sub = lane & 15;
  const int head = blockIdx.x & 15;       // consecutive blocks -> different heads
  const int dv0 = (blockIdx.x >> 4) * 16;
  const int col_local = tid >> 4;         // 0..15
  const int dv = dv0 + col_local;

  const float* qh = qn + (size_t)head * L_SEQ * 128;
  const float* kh = kn + (size_t)head * L_SEQ * 128;

  auto stage = [&](int chunk, int buf) {
    const int l0 = chunk * CH;
    const float* qg = qh + (size_t)l0 * 128;
    const float* kg = kh + (size_t)l0 * 128;
#pragma unroll
    for (int i = 0; i < 2; ++i) {
      int seg = i * 4 + wave;             // 8 segments of 256 floats
      int off = seg * 256 + lane * 4;
      gl_lds16(qg + off, &qs[buf][0][0] + seg * 256);
      gl_lds16(kg + off, &ks[buf][0][0] + seg * 256);
    }
    {  // v: 16 cols x CH steps = 256 floats, wave w stages cols 4w..4w+3
      int idx = wave * 64 + lane;         // col = idx>>4, step = idx&15
      gl_lds4(vT + (size_t)(head * 128 + dv0 + (idx >> 4)) * L_SEQ + l0 + (idx & 15),
              &vs[buf][0][0] + wave * 64);
    }
    if (wave == 0 && lane < 48) {         // e (0-15), beta (16-31), qk (32-47)
      const float* src = (lane < 16) ? (egT + head * L_SEQ + l0 + lane)
                       : (lane < 32) ? (btT + head * L_SEQ + l0 + (lane - 16))
                                     : (qkT + head * L_SEQ + l0 + (lane - 32));
      gl_lds4(src, &ebc[buf][0][0]);      // lane l -> flat [l]
    }
  };

  stage(0, 0);
  __syncthreads();

  f32x4 Mlo = {0.f, 0.f, 0.f, 0.f}, Mhi = {0.f, 0.f, 0.f, 0.f};
  const int dkb = dk_sub * 8;

#pragma unroll 1
  for (int c = 0; c < NCH; ++c) {
    const int buf = c & 1;
    if (c + 1 < NCH) stage(c + 1, buf ^ 1);

    // chunk-start bulk loads: all per-step scalars for 16 steps into regs
    f32x4 ev[4], bv[4], cv[4], vv[4];
#pragma unroll
    for (int i = 0; i < 4; ++i) {
      ev[i] = *(const f32x4*)&ebc[buf][0][i * 4];
      bv[i] = *(const f32x4*)&ebc[buf][1][i * 4];
      cv[i] = *(const f32x4*)&ebc[buf][2][i * 4];
      vv[i] = *(const f32x4*)&vs[buf][col_local][i * 4];
    }
    // q/k ring prefetch, distance 3
    f32x4 qr[4][2], kr[4][2];
#pragma unroll
    for (int i = 0; i < 3; ++i) {
      qr[i][0] = *(const f32x4*)&qs[buf][i][dkb];
      qr[i][1] = *(const f32x4*)&qs[buf][i][dkb + 4];
      kr[i][0] = *(const f32x4*)&ks[buf][i][dkb];
      kr[i][1] = *(const f32x4*)&ks[buf][i][dkb + 4];
    }

#pragma unroll
    for (int s = 0; s < CH; ++s) {
      if (s + 3 < CH) {
        qr[(s + 3) & 3][0] = *(const f32x4*)&qs[buf][s + 3][dkb];
        qr[(s + 3) & 3][1] = *(const f32x4*)&qs[buf][s + 3][dkb + 4];
        kr[(s + 3) & 3][0] = *(const f32x4*)&ks[buf][s + 3][dkb];
        kr[(s + 3) & 3][1] = *(const f32x4*)&ks[buf][s + 3][dkb + 4];
      }
      const f32x4 q0 = qr[s & 3][0], q1 = qr[s & 3][1];
      const f32x4 k0 = kr[s & 3][0], k1 = kr[s & 3][1];
      const float e = ev[s >> 2][s & 3], b = bv[s >> 2][s & 3];
      const float qk = cv[s >> 2][s & 3], v = vv[s >> 2][s & 3];

      // dots on M_old: two independent fma chains each, depth 4+1
      float skm0 = k0[0] * Mlo[0], skm1 = k0[1] * Mlo[1];
      float sqm0 = q0[0] * Mlo[0], sqm1 = q0[1] * Mlo[1];
      skm0 = fmaf(k0[2], Mlo[2], skm0); skm1 = fmaf(k0[3], Mlo[3], skm1);
      sqm0 = fmaf(q0[2], Mlo[2], sqm0); sqm1 = fmaf(q0[3], Mlo[3], sqm1);
      skm0 = fmaf(k1[0], Mhi[0], skm0); skm1 = fmaf(k1[1], Mhi[1], skm1);
      sqm0 = fmaf(q1[0], Mhi[0], sqm0); sqm1 = fmaf(q1[1], Mhi[1], sqm1);
      skm0 = fmaf(k1[2], Mhi[2], skm0); skm1 = fmaf(k1[3], Mhi[3], skm1);
      sqm0 = fmaf(q1[2], Mhi[2], sqm0); sqm1 = fmaf(q1[3], Mhi[3], sqm1);
      // e*M_old off the skm critical path (overlaps red16)
      f32x4 emlo, emhi;
#pragma unroll
      for (int i = 0; i < 4; ++i) { emlo[i] = e * Mlo[i]; emhi[i] = e * Mhi[i]; }
      float skm = red16(skm0 + skm1);
      float sqm = red16(sqm0 + sqm1);
      float dl = (v - e * skm) * b;       // delta
      float o = fmaf(qk, dl, e * sqm);    // q . M_new
      if (dk_sub == 0)
        oatt[(size_t)((c * CH + s) * 16 + head) * 128 + dv] = o;
#pragma unroll
      for (int i = 0; i < 4; ++i) {
        Mlo[i] = fmaf(k0[i], dl, emlo[i]);
        Mhi[i] = fmaf(k1[i], dl, emhi[i]);
      }
    }
    __syncthreads();
  }
}

// ---------------- gated RMSNorm -> bf16 ----------------
__global__ __launch_bounds__(256) void grms_kernel(const float* __restrict__ oatt,
                                                   const float* __restrict__ z,
                                                   const float* __restrict__ norm_w,
                                                   u16* __restrict__ gn) {
  int wid = blockIdx.x * 4 + (threadIdx.x >> 6);
  int lane = threadIdx.x & 63;
  int l = wid >> 4, h = wid & 15;
  const float* o = oatt + (size_t)wid * 128;
  f32x2 ov = *(const f32x2*)&o[lane * 2];
  float ss = ov[0] * ov[0] + ov[1] * ov[1];
#pragma unroll
  for (int s = 1; s < 64; s <<= 1) ss += __shfl_xor(ss, s);
  float r = 1.f / sqrtf(ss * (1.f / 128.f) + 1e-6f);
  const float* zp = z + (size_t)l * VALD + h * 128;
  f32x2 zv = *(const f32x2*)&zp[lane * 2];
  u16 r0, r1;
  {
    float sil = zv[0] / (1.f + expf(-zv[0]));
    r0 = f2bf(ov[0] * r * norm_w[lane * 2] * sil);
    float sil1 = zv[1] / (1.f + expf(-zv[1]));
    r1 = f2bf(ov[1] * r * norm_w[lane * 2 + 1] * sil1);
  }
  u16* dst = gn + (size_t)l * VALD + h * 128 + lane * 2;
  dst[0] = r0; dst[1] = r1;
}

extern "C" void kernel_launch(void* const* d_in, const int* in_sizes, int n_in,
                              void* d_out, int out_size, void* d_ws, size_t ws_size,
                              hipStream_t stream) {
  const float* x      = (const float*)d_in[0];
  const float* Wqkv   = (const float*)d_in[1];
  const float* Wz     = (const float*)d_in[2];
  const float* Wb     = (const float*)d_in[3];
  const float* Wa     = (const float*)d_in[4];
  const float* conv_w = (const float*)d_in[5];
  const float* A_log  = (const float*)d_in[6];
  const float* dt_bias= (const float*)d_in[7];
  const float* norm_w = (const float*)d_in[8];
  const float* Wout   = (const float*)d_in[9];
  float* out = (float*)d_out;

  char* ws = (char*)d_ws;
  size_t off = 0;
  auto alloc = [&](size_t bytes) {
    void* p = ws + off;
    off = (off + bytes + 255) & ~(size_t)255;
    return p;
  };
  u16* xb     = (u16*)alloc((size_t)L_SEQ * IDIM_ * 2);
  u16* WqkvT  = (u16*)alloc((size_t)CONVD * IDIM_ * 2);
  u16* WzT    = (u16*)alloc((size_t)VALD * IDIM_ * 2);
  u16* WoutT  = (u16*)alloc((size_t)IDIM_ * VALD * 2);
  float* qkv  = (float*)alloc((size_t)L_SEQ * CONVD * 4);
  float* qkvc = (float*)alloc((size_t)L_SEQ * CONVD * 4);
  float* zbuf = (float*)alloc((size_t)L_SEQ * VALD * 4);
  float* btT  = (float*)alloc((size_t)L_SEQ * H_ * 4);
  float* egT  = (float*)alloc((size_t)L_SEQ * H_ * 4);
  float* qkTb = (float*)alloc((size_t)L_SEQ * H_ * 4);
  float* oatt = (float*)alloc((size_t)L_SEQ * H_ * DV_ * 4);
  u16* gn     = (u16*)alloc((size_t)L_SEQ * VALD * 2);

  // qn/kn/vT reuse the dead qkv buffer after conv (exact 24MB fit)
  float* qn = qkv;
  float* kn = qn + (size_t)H_ * L_SEQ * 128;
  float* vT = kn + (size_t)H_ * L_SEQ * 128;

  // casts / transposes
  castx_kernel<<<(L_SEQ * IDIM_) / 1024, 256, 0, stream>>>(x, xb);
  tcast_kernel<<<dim3(CONVD / 32, IDIM_ / 32), 256, 0, stream>>>(Wqkv, WqkvT, IDIM_, CONVD);
  tcast_kernel<<<dim3(VALD / 32, IDIM_ / 32), 256, 0, stream>>>(Wz, WzT, IDIM_, VALD);
  tcast_kernel<<<dim3(IDIM_ / 32, VALD / 32), 256, 0, stream>>>(Wout, WoutT, VALD, IDIM_);

  // projections
  gemm_bt_kernel<<<dim3(CONVD / 128, L_SEQ / 128), 256, 0, stream>>>(xb, WqkvT, qkv, L_SEQ, CONVD, IDIM_);
  gemm_bt_kernel<<<dim3(VALD / 128, L_SEQ / 128), 256, 0, stream>>>(xb, WzT, zbuf, L_SEQ, VALD, IDIM_);

  // conv + silu, gates
  conv_silu_kernel<<<(L_SEQ * CONVD) / 256, 256, 0, stream>>>(qkv, conv_w, qkvc);
  betag_kernel<<<L_SEQ, 128, 0, stream>>>(x, Wb, Wa, A_log, dt_bias, btT, egT);

  // repack: q/k l2norm + qk scalar -> [h][l][dk] / qkT[h][l]; v -> [h*128+dv][l]
  l2qk_kernel<<<(L_SEQ * H_) / 4, 256, 0, stream>>>(qkvc, qn, kn, qkTb);
  vtrans_kernel<<<dim3(VALD / 32, L_SEQ / 32), 256, 0, stream>>>(qkvc, vT);

  // sequential scan (128 blocks, 512 waves — R6-exact)
  scan_kernel<<<H_ * (DV_ / 16), 256, 0, stream>>>(qn, kn, vT, egT, btT, qkTb, oatt);

  // gated rmsnorm + final projection
  grms_kernel<<<(L_SEQ * H_) / 4, 256, 0, stream>>>(oatt, zbuf, norm_w, gn);
  gemm_bt_kernel<<<dim3(IDIM_ / 128, L_SEQ / 128), 256, 0, stream>>>(gn, WoutT, out, L_SEQ, IDIM_, VALD);
}

// Round 10
// 382.983 us; speedup vs baseline: 1.9281x; 1.0684x over previous
//
#include <hip/hip_runtime.h>

typedef short bf16x8 __attribute__((ext_vector_type(8)));
typedef float f32x4 __attribute__((ext_vector_type(4)));
typedef float f32x2 __attribute__((ext_vector_type(2)));
typedef unsigned short u16;
typedef u16 u16x4 __attribute__((ext_vector_type(4)));

#define L_SEQ 1024
#define IDIM_ 2048
#define H_ 16
#define DK_ 128
#define DV_ 128
#define KEYD 2048
#define VALD 2048
#define CONVD 6144
#define QZD 8192          // combined qkv+z projection width
#define CH 16
#define NCH (L_SEQ / CH)

__device__ __forceinline__ u16 f2bf(float f) {
  union { float f; unsigned u; } v; v.f = f;
  unsigned r = v.u + 0x7FFF + ((v.u >> 16) & 1);  // RNE
  return (u16)(r >> 16);
}

// 16-lane allreduce, all-DPP (VALU only). Verified R3-R9.
__device__ __forceinline__ float red16(float x) {
  union U { float f; int i; } a, t;
  a.f = x;
  t.i = __builtin_amdgcn_update_dpp(0, a.i, 0xB1, 0xF, 0xF, true); a.f += t.f;
  t.i = __builtin_amdgcn_update_dpp(0, a.i, 0x4E, 0xF, 0xF, true); a.f += t.f;
  t.i = __builtin_amdgcn_update_dpp(0, a.i, 0x141, 0xF, 0xF, true); a.f += t.f;
  t.i = __builtin_amdgcn_update_dpp(0, a.i, 0x140, 0xF, 0xF, true); a.f += t.f;
  return a.f;
}

__device__ __forceinline__ void gl_lds16(const float* g, float* l) {
  __builtin_amdgcn_global_load_lds(
      (const __attribute__((address_space(1))) void*)g,
      (__attribute__((address_space(3))) void*)l, 16, 0, 0);
}
__device__ __forceinline__ void gl_lds4(const float* g, float* l) {
  __builtin_amdgcn_global_load_lds(
      (const __attribute__((address_space(1))) void*)g,
      (__attribute__((address_space(3))) void*)l, 4, 0, 0);
}

// ---------------- cast x (f32 -> bf16), vectorized x4 ----------------
__global__ __launch_bounds__(256) void castx_kernel(const float* __restrict__ x,
                                                    u16* __restrict__ xb) {
  int i = (blockIdx.x * 256 + threadIdx.x) * 4;
  f32x4 v = *(const f32x4*)&x[i];
  u16x4 o = { f2bf(v[0]), f2bf(v[1]), f2bf(v[2]), f2bf(v[3]) };
  *(u16x4*)&xb[i] = o;
}

// ------------- transpose + cast: W[R][C] f32 -> WT[C][R] bf16 -------------
__global__ __launch_bounds__(256) void tcast_kernel(const float* __restrict__ W,
                                                    u16* __restrict__ WT,
                                                    int R, int C) {
  __shared__ float tile[32][33];
  int c0 = blockIdx.x * 32, r0 = blockIdx.y * 32;
  int tx = threadIdx.x & 31, ty = threadIdx.x >> 5;  // 32 x 8
#pragma unroll
  for (int j = 0; j < 4; ++j)
    tile[ty + j * 8][tx] = W[(size_t)(r0 + ty + j * 8) * C + c0 + tx];
  __syncthreads();
#pragma unroll
  for (int j = 0; j < 4; ++j)
    WT[(size_t)(c0 + ty + j * 8) * R + r0 + tx] = f2bf(tile[tx][ty + j * 8]);
}

// ---------------- NT GEMM: A[M,K] bf16, B[N,K] bf16 -> C[M,N] f32 ----------------
// 128x128 tile, BK=64, 4 waves (2x2 of 64x64). Padded reg-staged LDS (R6-exact).
__global__ __launch_bounds__(256) void gemm_bt_kernel(const u16* __restrict__ A,
                                                      const u16* __restrict__ B,
                                                      float* __restrict__ C,
                                                      int M, int N, int K) {
  __shared__ short As[128 * 72];
  __shared__ short Bs[128 * 72];
  const int tid = threadIdx.x;
  const int lane = tid & 63, wave = tid >> 6;
  const int wm = wave >> 1, wn = wave & 1;
  const int m0 = blockIdx.y * 128, n0 = blockIdx.x * 128;
  const int l15 = lane & 15, lhi = lane >> 4;

  f32x4 acc[4][4] = {};

  for (int k0 = 0; k0 < K; k0 += 64) {
    __syncthreads();
#pragma unroll
    for (int i = 0; i < 4; ++i) {
      int chunk = tid + i * 256;
      int row = chunk >> 3;
      int kc = (chunk & 7) * 8;
      *(bf16x8*)&As[row * 72 + kc] =
          *(const bf16x8*)&A[(size_t)(m0 + row) * K + k0 + kc];
      *(bf16x8*)&Bs[row * 72 + kc] =
          *(const bf16x8*)&B[(size_t)(n0 + row) * K + k0 + kc];
    }
    __syncthreads();
#pragma unroll
    for (int kk = 0; kk < 64; kk += 32) {
      const int koff = kk + lhi * 8;
      bf16x8 a[4], b[4];
#pragma unroll
      for (int m = 0; m < 4; ++m)
        a[m] = *(const bf16x8*)&As[(wm * 64 + m * 16 + l15) * 72 + koff];
#pragma unroll
      for (int n = 0; n < 4; ++n)
        b[n] = *(const bf16x8*)&Bs[(wn * 64 + n * 16 + l15) * 72 + koff];
#pragma unroll
      for (int m = 0; m < 4; ++m)
#pragma unroll
        for (int n = 0; n < 4; ++n)
          acc[m][n] = __builtin_amdgcn_mfma_f32_16x16x32_bf16(a[m], b[n], acc[m][n], 0, 0, 0);
    }
  }
#pragma unroll
  for (int m = 0; m < 4; ++m)
#pragma unroll
    for (int n = 0; n < 4; ++n)
#pragma unroll
      for (int j = 0; j < 4; ++j) {
        int row = m0 + wm * 64 + m * 16 + lhi * 4 + j;
        int col = n0 + wn * 64 + n * 16 + l15;
        C[(size_t)row * N + col] = acc[m][n][j];
      }
}

// ---------------- NT GEMM, BM=64 variant (for M=1024,N=2048: 256 blocks = 1/CU) ----
__global__ __launch_bounds__(256) void gemm_bt64_kernel(const u16* __restrict__ A,
                                                        const u16* __restrict__ B,
                                                        float* __restrict__ C,
                                                        int M, int N, int K) {
  __shared__ short As[64 * 72];
  __shared__ short Bs[128 * 72];
  const int tid = threadIdx.x;
  const int lane = tid & 63, wave = tid >> 6;
  const int wm = wave >> 1, wn = wave & 1;       // 2x2 waves over (64,128)
  const int m0 = blockIdx.y * 64, n0 = blockIdx.x * 128;
  const int l15 = lane & 15, lhi = lane >> 4;

  f32x4 acc[2][4] = {};

  for (int k0 = 0; k0 < K; k0 += 64) {
    __syncthreads();
#pragma unroll
    for (int i = 0; i < 2; ++i) {       // A: 64 rows x 8 chunks = 512
      int chunk = tid + i * 256;
      int row = chunk >> 3;
      int kc = (chunk & 7) * 8;
      *(bf16x8*)&As[row * 72 + kc] =
          *(const bf16x8*)&A[(size_t)(m0 + row) * K + k0 + kc];
    }
#pragma unroll
    for (int i = 0; i < 4; ++i) {       // B: 128 rows x 8 chunks = 1024
      int chunk = tid + i * 256;
      int row = chunk >> 3;
      int kc = (chunk & 7) * 8;
      *(bf16x8*)&Bs[row * 72 + kc] =
          *(const bf16x8*)&B[(size_t)(n0 + row) * K + k0 + kc];
    }
    __syncthreads();
#pragma unroll
    for (int kk = 0; kk < 64; kk += 32) {
      const int koff = kk + lhi * 8;
      bf16x8 a[2], b[4];
#pragma unroll
      for (int m = 0; m < 2; ++m)
        a[m] = *(const bf16x8*)&As[(wm * 32 + m * 16 + l15) * 72 + koff];
#pragma unroll
      for (int n = 0; n < 4; ++n)
        b[n] = *(const bf16x8*)&Bs[(wn * 64 + n * 16 + l15) * 72 + koff];
#pragma unroll
      for (int m = 0; m < 2; ++m)
#pragma unroll
        for (int n = 0; n < 4; ++n)
          acc[m][n] = __builtin_amdgcn_mfma_f32_16x16x32_bf16(a[m], b[n], acc[m][n], 0, 0, 0);
    }
  }
#pragma unroll
  for (int m = 0; m < 2; ++m)
#pragma unroll
    for (int n = 0; n < 4; ++n)
#pragma unroll
      for (int j = 0; j < 4; ++j) {
        int row = m0 + wm * 32 + m * 16 + lhi * 4 + j;
        int col = n0 + wn * 64 + n * 16 + l15;
        C[(size_t)row * N + col] = acc[m][n][j];
      }
}

// -------- beta/eg gates, written TRANSPOSED: egT/btT[h*1024 + l] --------
__global__ __launch_bounds__(128) void betag_kernel(const float* __restrict__ x,
                                                    const float* __restrict__ Wb,
                                                    const float* __restrict__ Wa,
                                                    const float* __restrict__ A_log,
                                                    const float* __restrict__ dt_bias,
                                                    float* __restrict__ btT,
                                                    float* __restrict__ egT) {
  int l = blockIdx.x;
  __shared__ float xs[IDIM_];
  __shared__ float redb[128], reda[128];
  for (int i = threadIdx.x; i < IDIM_; i += 128) xs[i] = x[(size_t)l * IDIM_ + i];
  __syncthreads();
  int h = threadIdx.x & 15, part = threadIdx.x >> 4;
  float sb = 0.f, sa = 0.f;
  int d0 = part * 256;
  for (int d = d0; d < d0 + 256; ++d) {
    float xv = xs[d];
    sb += xv * Wb[d * 16 + h];
    sa += xv * Wa[d * 16 + h];
  }
  redb[threadIdx.x] = sb;
  reda[threadIdx.x] = sa;
  __syncthreads();
  if (threadIdx.x < 16) {
    float b = 0.f, a = 0.f;
#pragma unroll
    for (int p = 0; p < 8; ++p) { b += redb[p * 16 + h]; a += reda[p * 16 + h]; }
    btT[h * L_SEQ + l] = 1.f / (1.f + expf(-b));
    float dtv = a + dt_bias[h];
    dtv = (dtv > 20.f) ? dtv : log1pf(expf(dtv));
    float g = -expf(A_log[h]) * dtv;
    egT[h * L_SEQ + l] = expf(g);
  }
}

// ---- fused conv+SiLU+l2norm for q,k from raw qkvz; repack [h][l][dk], qkT ----
__global__ __launch_bounds__(256) void l2qk_kernel(const float* __restrict__ qkvz,
                                                   const float* __restrict__ cw,
                                                   float* __restrict__ qn,
                                                   float* __restrict__ kn,
                                                   float* __restrict__ qkT) {
  int wid = blockIdx.x * 4 + (threadIdx.x >> 6);  // 16384 waves: l*16+h
  int lane = threadIdx.x & 63;
  int l = wid >> 4, h = wid & 15;
  const int cq = h * 128 + lane * 2;
  const int ck = KEYD + cq;
  const float* row0 = qkvz + (size_t)l * QZD;
  f32x4 wq0 = *(const f32x4*)&cw[cq * 4];
  f32x4 wq1 = *(const f32x4*)&cw[(cq + 1) * 4];
  f32x4 wk0 = *(const f32x4*)&cw[ck * 4];
  f32x4 wk1 = *(const f32x4*)&cw[(ck + 1) * 4];
  f32x2 xq = *(const f32x2*)&row0[cq];
  f32x2 xk = *(const f32x2*)&row0[ck];
  float q0 = xq[0] * wq0[3], q1 = xq[1] * wq1[3];
  float k0 = xk[0] * wk0[3], k1 = xk[1] * wk1[3];
  if (l >= 1) {
    f32x2 aq = *(const f32x2*)&row0[cq - QZD];
    f32x2 ak = *(const f32x2*)&row0[ck - QZD];
    q0 += aq[0] * wq0[2]; q1 += aq[1] * wq1[2];
    k0 += ak[0] * wk0[2]; k1 += ak[1] * wk1[2];
  }
  if (l >= 2) {
    f32x2 aq = *(const f32x2*)&row0[cq - 2 * QZD];
    f32x2 ak = *(const f32x2*)&row0[ck - 2 * QZD];
    q0 += aq[0] * wq0[1]; q1 += aq[1] * wq1[1];
    k0 += ak[0] * wk0[1]; k1 += ak[1] * wk1[1];
  }
  if (l >= 3) {
    f32x2 aq = *(const f32x2*)&row0[cq - 3 * QZD];
    f32x2 ak = *(const f32x2*)&row0[ck - 3 * QZD];
    q0 += aq[0] * wq0[0]; q1 += aq[1] * wq1[0];
    k0 += ak[0] * wk0[0]; k1 += ak[1] * wk1[0];
  }
  f32x2 qv = { q0 / (1.f + expf(-q0)), q1 / (1.f + expf(-q1)) };
  f32x2 kv = { k0 / (1.f + expf(-k0)), k1 / (1.f + expf(-k1)) };

  float ssq = qv[0] * qv[0] + qv[1] * qv[1];
  float ssk = kv[0] * kv[0] + kv[1] * kv[1];
#pragma unroll
  for (int s = 1; s < 64; s <<= 1) {
    ssq += __shfl_xor(ssq, s);
    ssk += __shfl_xor(ssk, s);
  }
  float scq = 0.08838834764831845f / sqrtf(ssq + 1e-6f);  // * DK^-0.5
  float sck = 1.f / sqrtf(ssk + 1e-6f);
  qv[0] *= scq; qv[1] *= scq;
  kv[0] *= sck; kv[1] *= sck;
  size_t base = ((size_t)h * L_SEQ + l) * 128 + lane * 2;
  *(f32x2*)&qn[base] = qv;
  *(f32x2*)&kn[base] = kv;
  float qk = qv[0] * kv[0] + qv[1] * kv[1];
#pragma unroll
  for (int s = 1; s < 64; s <<= 1) qk += __shfl_xor(qk, s);
  if (lane == 0) qkT[h * L_SEQ + l] = qk;
}

// ---- fused conv+SiLU + transpose of v slice -> vT[c][l], c = h*128+dv ----
__global__ __launch_bounds__(256) void vtrans_kernel(const float* __restrict__ qkvz,
                                                     const float* __restrict__ cw,
                                                     float* __restrict__ vT) {
  __shared__ float tile[32][33];
  int c0 = blockIdx.x * 32, l0 = blockIdx.y * 32;
  int tx = threadIdx.x & 31, ty = threadIdx.x >> 5;
  const int c = 2 * KEYD + c0 + tx;
  f32x4 w = *(const f32x4*)&cw[c * 4];
#pragma unroll
  for (int j = 0; j < 4; ++j) {
    int l = l0 + ty + j * 8;
    const float* p = qkvz + (size_t)l * QZD + c;
    float s = p[0] * w[3];
    if (l >= 1) s += p[-QZD] * w[2];
    if (l >= 2) s += p[-2 * QZD] * w[1];
    if (l >= 3) s += p[-3 * QZD] * w[0];
    tile[ty + j * 8][tx] = s / (1.f + expf(-s));
  }
  __syncthreads();
#pragma unroll
  for (int j = 0; j < 4; ++j)
    vT[(size_t)(c0 + ty + j * 8) * L_SEQ + l0 + tx] = tile[tx][ty + j * 8];
}

// ---------------- sequential delta-rule scan (R6-exact, 160us known-good) ----
__global__ __launch_bounds__(256) void scan_kernel(const float* __restrict__ qn,
                                                   const float* __restrict__ kn,
                                                   const float* __restrict__ vT,
                                                   const float* __restrict__ egT,
                                                   const float* __restrict__ btT,
                                                   const float* __restrict__ qkT,
                                                   float* __restrict__ oatt) {
  __shared__ alignas(16) float qs[2][CH][128];
  __shared__ alignas(16) float ks[2][CH][128];
  __shared__ alignas(16) float vs[2][16][CH];
  __shared__ alignas(16) float ebc[2][3][CH];

  const int tid = threadIdx.x;
  const int wave = tid >> 6, lane = tid & 63;
  const int dk_sub = lane & 15;
  const int head = blockIdx.x & 15;
  const int dv0 = (blockIdx.x >> 4) * 16;
  const int col_local = tid >> 4;
  const int dv = dv0 + col_local;

  const float* qh = qn + (size_t)head * L_SEQ * 128;
  const float* kh = kn + (size_t)head * L_SEQ * 128;

  auto stage = [&](int chunk, int buf) {
    const int l0 = chunk * CH;
    const float* qg = qh + (size_t)l0 * 128;
    const float* kg = kh + (size_t)l0 * 128;
#pragma unroll
    for (int i = 0; i < 2; ++i) {
      int seg = i * 4 + wave;
      int off = seg * 256 + lane * 4;
      gl_lds16(qg + off, &qs[buf][0][0] + seg * 256);
      gl_lds16(kg + off, &ks[buf][0][0] + seg * 256);
    }
    {
      int idx = wave * 64 + lane;
      gl_lds4(vT + (size_t)(head * 128 + dv0 + (idx >> 4)) * L_SEQ + l0 + (idx & 15),
              &vs[buf][0][0] + wave * 64);
    }
    if (wave == 0 && lane < 48) {
      const float* src = (lane < 16) ? (egT + head * L_SEQ + l0 + lane)
                       : (lane < 32) ? (btT + head * L_SEQ + l0 + (lane - 16))
                                     : (qkT + head * L_SEQ + l0 + (lane - 32));
      gl_lds4(src, &ebc[buf][0][0]);
    }
  };

  stage(0, 0);
  __syncthreads();

  f32x4 Mlo = {0.f, 0.f, 0.f, 0.f}, Mhi = {0.f, 0.f, 0.f, 0.f};
  const int dkb = dk_sub * 8;

#pragma unroll 1
  for (int c = 0; c < NCH; ++c) {
    const int buf = c & 1;
    if (c + 1 < NCH) stage(c + 1, buf ^ 1);

    f32x4 ev[4], bv[4], cv[4], vv[4];
#pragma unroll
    for (int i = 0; i < 4; ++i) {
      ev[i] = *(const f32x4*)&ebc[buf][0][i * 4];
      bv[i] = *(const f32x4*)&ebc[buf][1][i * 4];
      cv[i] = *(const f32x4*)&ebc[buf][2][i * 4];
      vv[i] = *(const f32x4*)&vs[buf][col_local][i * 4];
    }
    f32x4 qr[4][2], kr[4][2];
#pragma unroll
    for (int i = 0; i < 3; ++i) {
      qr[i][0] = *(const f32x4*)&qs[buf][i][dkb];
      qr[i][1] = *(const f32x4*)&qs[buf][i][dkb + 4];
      kr[i][0] = *(const f32x4*)&ks[buf][i][dkb];
      kr[i][1] = *(const f32x4*)&ks[buf][i][dkb + 4];
    }

#pragma unroll
    for (int s = 0; s < CH; ++s) {
      if (s + 3 < CH) {
        qr[(s + 3) & 3][0] = *(const f32x4*)&qs[buf][s + 3][dkb];
        qr[(s + 3) & 3][1] = *(const f32x4*)&qs[buf][s + 3][dkb + 4];
        kr[(s + 3) & 3][0] = *(const f32x4*)&ks[buf][s + 3][dkb];
        kr[(s + 3) & 3][1] = *(const f32x4*)&ks[buf][s + 3][dkb + 4];
      }
      const f32x4 q0 = qr[s & 3][0], q1 = qr[s & 3][1];
      const f32x4 k0 = kr[s & 3][0], k1 = kr[s & 3][1];
      const float e = ev[s >> 2][s & 3], b = bv[s >> 2][s & 3];
      const float qk = cv[s >> 2][s & 3], v = vv[s >> 2][s & 3];

      float skm0 = k0[0] * Mlo[0], skm1 = k0[1] * Mlo[1];
      float sqm0 = q0[0] * Mlo[0], sqm1 = q0[1] * Mlo[1];
      skm0 = fmaf(k0[2], Mlo[2], skm0); skm1 = fmaf(k0[3], Mlo[3], skm1);
      sqm0 = fmaf(q0[2], Mlo[2], sqm0); sqm1 = fmaf(q0[3], Mlo[3], sqm1);
      skm0 = fmaf(k1[0], Mhi[0], skm0); skm1 = fmaf(k1[1], Mhi[1], skm1);
      sqm0 = fmaf(q1[0], Mhi[0], sqm0); sqm1 = fmaf(q1[1], Mhi[1], sqm1);
      skm0 = fmaf(k1[2], Mhi[2], skm0); skm1 = fmaf(k1[3], Mhi[3], skm1);
      sqm0 = fmaf(q1[2], Mhi[2], sqm0); sqm1 = fmaf(q1[3], Mhi[3], sqm1);
      f32x4 emlo, emhi;
#pragma unroll
      for (int i = 0; i < 4; ++i) { emlo[i] = e * Mlo[i]; emhi[i] = e * Mhi[i]; }
      float skm = red16(skm0 + skm1);
      float sqm = red16(sqm0 + sqm1);
      float dl = (v - e * skm) * b;
      float o = fmaf(qk, dl, e * sqm);
      if (dk_sub == 0)
        oatt[(size_t)((c * CH + s) * 16 + head) * 128 + dv] = o;
#pragma unroll
      for (int i = 0; i < 4; ++i) {
        Mlo[i] = fmaf(k0[i], dl, emlo[i]);
        Mhi[i] = fmaf(k1[i], dl, emhi[i]);
      }
    }
    __syncthreads();
  }
}

// ---------------- gated RMSNorm -> bf16 (z read from qkvz cols 6144+) ----------
__global__ __launch_bounds__(256) void grms_kernel(const float* __restrict__ oatt,
                                                   const float* __restrict__ qkvz,
                                                   const float* __restrict__ norm_w,
                                                   u16* __restrict__ gn) {
  int wid = blockIdx.x * 4 + (threadIdx.x >> 6);
  int lane = threadIdx.x & 63;
  int l = wid >> 4, h = wid & 15;
  const float* o = oatt + (size_t)wid * 128;
  f32x2 ov = *(const f32x2*)&o[lane * 2];
  float ss = ov[0] * ov[0] + ov[1] * ov[1];
#pragma unroll
  for (int s = 1; s < 64; s <<= 1) ss += __shfl_xor(ss, s);
  float r = 1.f / sqrtf(ss * (1.f / 128.f) + 1e-6f);
  const float* zp = qkvz + (size_t)l * QZD + CONVD + h * 128;
  f32x2 zv = *(const f32x2*)&zp[lane * 2];
  u16 r0, r1;
  {
    float sil = zv[0] / (1.f + expf(-zv[0]));
    r0 = f2bf(ov[0] * r * norm_w[lane * 2] * sil);
    float sil1 = zv[1] / (1.f + expf(-zv[1]));
    r1 = f2bf(ov[1] * r * norm_w[lane * 2 + 1] * sil1);
  }
  u16* dst = gn + (size_t)l * VALD + h * 128 + lane * 2;
  dst[0] = r0; dst[1] = r1;
}

extern "C" void kernel_launch(void* const* d_in, const int* in_sizes, int n_in,
                              void* d_out, int out_size, void* d_ws, size_t ws_size,
                              hipStream_t stream) {
  const float* x      = (const float*)d_in[0];
  const float* Wqkv   = (const float*)d_in[1];
  const float* Wz     = (const float*)d_in[2];
  const float* Wb     = (const float*)d_in[3];
  const float* Wa     = (const float*)d_in[4];
  const float* conv_w = (const float*)d_in[5];
  const float* A_log  = (const float*)d_in[6];
  const float* dt_bias= (const float*)d_in[7];
  const float* norm_w = (const float*)d_in[8];
  const float* Wout   = (const float*)d_in[9];
  float* out = (float*)d_out;

  char* ws = (char*)d_ws;
  size_t off = 0;
  auto alloc = [&](size_t bytes) {
    void* p = ws + off;
    off = (off + bytes + 255) & ~(size_t)255;
    return p;
  };
  u16* xb     = (u16*)alloc((size_t)L_SEQ * IDIM_ * 2);
  u16* WcatT  = (u16*)alloc((size_t)QZD * IDIM_ * 2);    // rows 0..6143 Wqkv^T, 6144.. Wz^T
  u16* WoutT  = (u16*)alloc((size_t)IDIM_ * VALD * 2);
  float* qkvz = (float*)alloc((size_t)L_SEQ * QZD * 4);  // combined qkv+z projection
  float* qn   = (float*)alloc((size_t)H_ * L_SEQ * 128 * 4);
  float* kn   = (float*)alloc((size_t)H_ * L_SEQ * 128 * 4);
  float* vT   = (float*)alloc((size_t)H_ * 128 * L_SEQ * 4);
  float* btT  = (float*)alloc((size_t)L_SEQ * H_ * 4);
  float* egT  = (float*)alloc((size_t)L_SEQ * H_ * 4);
  float* qkTb = (float*)alloc((size_t)L_SEQ * H_ * 4);
  float* oatt = (float*)alloc((size_t)L_SEQ * H_ * DV_ * 4);
  u16* gn     = (u16*)alloc((size_t)L_SEQ * VALD * 2);

  // casts / transposes
  castx_kernel<<<(L_SEQ * IDIM_) / 1024, 256, 0, stream>>>(x, xb);
  tcast_kernel<<<dim3(CONVD / 32, IDIM_ / 32), 256, 0, stream>>>(Wqkv, WcatT, IDIM_, CONVD);
  tcast_kernel<<<dim3(VALD / 32, IDIM_ / 32), 256, 0, stream>>>(Wz, WcatT + (size_t)CONVD * IDIM_, IDIM_, VALD);
  tcast_kernel<<<dim3(IDIM_ / 32, VALD / 32), 256, 0, stream>>>(Wout, WoutT, VALD, IDIM_);

  // combined projection: [qkv | z] in one GEMM (512 blocks = 2/CU exact)
  gemm_bt_kernel<<<dim3(QZD / 128, L_SEQ / 128), 256, 0, stream>>>(xb, WcatT, qkvz, L_SEQ, QZD, IDIM_);

  // gates
  betag_kernel<<<L_SEQ, 128, 0, stream>>>(x, Wb, Wa, A_log, dt_bias, btT, egT);

  // fused conv+silu+l2norm+qk repack; fused conv+silu+v transpose
  l2qk_kernel<<<(L_SEQ * H_) / 4, 256, 0, stream>>>(qkvz, conv_w, qn, kn, qkTb);
  vtrans_kernel<<<dim3(VALD / 32, L_SEQ / 32), 256, 0, stream>>>(qkvz, conv_w, vT);

  // sequential scan (128 blocks, 512 waves — R6-exact)
  scan_kernel<<<H_ * (DV_ / 16), 256, 0, stream>>>(qn, kn, vT, egT, btT, qkTb, oatt);

  // gated rmsnorm + final projection (BM=64 -> 256 blocks = 1/CU)
  grms_kernel<<<(L_SEQ * H_) / 4, 256, 0, stream>>>(oatt, qkvz, norm_w, gn);
  gemm_bt64_kernel<<<dim3(IDIM_ / 128, L_SEQ / 64), 256, 0, stream>>>(gn, WoutT, out, L_SEQ, IDIM_, VALD);
}